// Round 1
// baseline (2402.328 us; speedup 1.0000x reference)
//
#include <hip/hip_runtime.h>
#include <hip/hip_bf16.h>
#include <math.h>

// Problem constants (shapes fixed by the reference)
#define BS   8192   // batch*seq tokens
#define SEQQ 2048   // seq
#define NB_  4      // batch
#define HID  1024
#define ES   2048   // n_exp * slots = 16*128
#define FFN  2730
#define NEXP 16
#define SLOT 128

// ---------------- softmax statistics kernels ----------------

// dispatch: softmax over seq dim (per batch, per expert-slot column).
// Output: dmax[b*ES+c], drcp[b*ES+c] = 1/sum(exp(l - max)) over the 2048 rows.
__global__ __launch_bounds__(256) void dispatch_stats(const float* __restrict__ L,
                                                      float* __restrict__ dmax,
                                                      float* __restrict__ drcp)
{
    int b  = blockIdx.x >> 6;          // 4 batches x 64 col-tiles of 32
    int c0 = (blockIdx.x & 63) * 32;
    int tc = threadIdx.x & 31;
    int rg = threadIdx.x >> 5;         // 0..7 row groups
    int c  = c0 + tc;
    const float* base = L + (size_t)b * SEQQ * ES + c;

    float mx = -1e30f;
    for (int r = rg; r < SEQQ; r += 8)
        mx = fmaxf(mx, base[(size_t)r * ES]);

    __shared__ float red[8][33];
    red[rg][tc] = mx;
    __syncthreads();
    if (rg == 0) {
        #pragma unroll
        for (int i = 1; i < 8; ++i) mx = fmaxf(mx, red[i][tc]);
        red[0][tc] = mx;
    }
    __syncthreads();
    mx = red[0][tc];
    __syncthreads();

    float s = 0.f;
    for (int r = rg; r < SEQQ; r += 8)
        s += __expf(base[(size_t)r * ES] - mx);
    red[rg][tc] = s;
    __syncthreads();
    if (rg == 0) {
        #pragma unroll
        for (int i = 1; i < 8; ++i) s += red[i][tc];
        dmax[b * ES + c] = mx;
        drcp[b * ES + c] = 1.f / s;
    }
}

// combine: softmax over the 2048 expert-slots per token (row softmax).
__global__ __launch_bounds__(256) void combine_stats(const float* __restrict__ L,
                                                     float* __restrict__ cmax,
                                                     float* __restrict__ crcp)
{
    int t = blockIdx.x;
    const float* row = L + (size_t)t * ES;
    int tid = threadIdx.x;
    int wave = tid >> 6, lane = tid & 63;

    float mx = -1e30f;
    for (int i = tid; i < ES; i += 256) mx = fmaxf(mx, row[i]);
    #pragma unroll
    for (int off = 32; off > 0; off >>= 1) mx = fmaxf(mx, __shfl_down(mx, off, 64));
    __shared__ float sm[4];
    __shared__ float sbc;
    if (lane == 0) sm[wave] = mx;
    __syncthreads();
    if (tid == 0) sbc = fmaxf(fmaxf(sm[0], sm[1]), fmaxf(sm[2], sm[3]));
    __syncthreads();
    mx = sbc;

    float s = 0.f;
    for (int i = tid; i < ES; i += 256) s += __expf(row[i] - mx);
    #pragma unroll
    for (int off = 32; off > 0; off >>= 1) s += __shfl_down(s, off, 64);
    __syncthreads();
    if (lane == 0) sm[wave] = s;
    __syncthreads();
    if (tid == 0) {
        cmax[t] = mx;
        crcp[t] = 1.f / (sm[0] + sm[1] + sm[2] + sm[3]);
    }
}

// ---------------- templated fp32 tiled GEMM ----------------
// C[M][N] = op(A) @ B, BK=16, 256 threads, micro-tile TM x TN per thread.
// AMODE 0: A row-major [M][K] (lda)
// AMODE 1: A K-major [K][M] (lda), element = exp(A - dmax[b(k),m]) * drcp[b(k),m]  (dispatch^T)
// AMODE 2: A row-major [M][K], element = exp(A - aux0[m])                           (combine)
// EPI 0: none; 1: silu; 2: multiply row by aux1[m]
// NBND: bounds-check N against Ndim; KBND: bounds-check K against Kdim
template<int BM, int BN, int TM, int TN, int AMODE, int EPI, bool NBND, bool KBND>
__global__ __launch_bounds__(256)
void gemm_kernel(const float* __restrict__ A, const float* __restrict__ B,
                 float* __restrict__ C,
                 int Ndim, int Kdim, int lda, int ldb, int ldc,
                 long sA, long sB, long sC,
                 const float* __restrict__ aux0, const float* __restrict__ aux1)
{
    constexpr int BK = 16;
    A += (size_t)blockIdx.z * sA;
    B += (size_t)blockIdx.z * sB;
    C += (size_t)blockIdx.z * sC;
    const int m0 = blockIdx.x * BM;
    const int n0 = blockIdx.y * BN;

    __shared__ float As[BK][BM + 4];
    __shared__ float Bs[BK][BN + 4];

    const int tid = threadIdx.x;
    const int txn = tid % (BN / TN);
    const int tym = tid / (BN / TN);

    float acc[TM][TN];
    #pragma unroll
    for (int i = 0; i < TM; ++i)
        #pragma unroll
        for (int j = 0; j < TN; ++j) acc[i][j] = 0.f;

    for (int k0 = 0; k0 < Kdim; k0 += BK) {
        // ---- stage A ----
        #pragma unroll
        for (int i = 0; i < BM * BK / 256; ++i) {
            int e = tid + 256 * i;
            if (AMODE == 1) {
                int kk = e / BM, mm = e % BM;
                int k = k0 + kk, m = m0 + mm;
                float v = A[(size_t)k * lda + m];
                int b = k >> 11;  // k / SEQQ
                As[kk][mm] = __expf(v - aux0[b * ES + m]) * aux1[b * ES + m];
            } else {
                int mm = e / BK, kk = e % BK;
                int k = k0 + kk, m = m0 + mm;
                float v = 0.f;
                if (!(KBND && k >= Kdim)) v = A[(size_t)m * lda + k];
                if (AMODE == 2) v = __expf(v - aux0[m]);
                As[kk][mm] = v;
            }
        }
        // ---- stage B ----
        #pragma unroll
        for (int i = 0; i < BN * BK / 256; ++i) {
            int e = tid + 256 * i;
            int kk = e / BN, nn = e % BN;
            int k = k0 + kk, n = n0 + nn;
            float v = 0.f;
            bool ok = true;
            if (NBND && n >= Ndim) ok = false;
            if (KBND && k >= Kdim) ok = false;
            if (ok) v = B[(size_t)k * ldb + n];
            Bs[kk][nn] = v;
        }
        __syncthreads();

        #pragma unroll
        for (int kk = 0; kk < BK; ++kk) {
            float a[TM], bb[TN];
            #pragma unroll
            for (int i = 0; i < TM; ++i) a[i] = As[kk][tym * TM + i];
            #pragma unroll
            for (int j = 0; j < TN; ++j) bb[j] = Bs[kk][txn * TN + j];
            #pragma unroll
            for (int i = 0; i < TM; ++i)
                #pragma unroll
                for (int j = 0; j < TN; ++j)
                    acc[i][j] = fmaf(a[i], bb[j], acc[i][j]);
        }
        __syncthreads();
    }

    // ---- epilogue ----
    #pragma unroll
    for (int i = 0; i < TM; ++i) {
        int m = m0 + tym * TM + i;
        #pragma unroll
        for (int j = 0; j < TN; ++j) {
            int n = n0 + txn * TN + j;
            if (NBND && n >= Ndim) continue;
            float v = acc[i][j];
            if (EPI == 1) v = v / (1.f + __expf(-v));       // silu
            else if (EPI == 2) v = v * aux1[m];             // 1/csum row scale
            C[(size_t)m * ldc + n] = v;
        }
    }
}

// ---------------- launch ----------------

extern "C" void kernel_launch(void* const* d_in, const int* in_sizes, int n_in,
                              void* d_out, int out_size, void* d_ws, size_t ws_size,
                              hipStream_t stream)
{
    const float* x      = (const float*)d_in[0];
    const float* logits = (const float*)d_in[1];   // [BS][ES] flat
    const float* w_up   = (const float*)d_in[2];   // [16][1024][2730]
    const float* w_down = (const float*)d_in[3];   // [16][2730][1024]
    float* y  = (float*)d_out;                     // [BS][HID]
    float* ws = (float*)d_ws;

    float* dmax = ws;                       // 4*2048
    float* drcp = ws + 8192;                // 4*2048
    float* cmax = ws + 16384;               // 8192
    float* crcp = ws + 24576;               // 8192
    float* xt   = ws + 32768;               // 2048*1024
    float* h    = xt + 2048 * 1024;         // 16*128*2730
    float* eout = h + (size_t)NEXP * SLOT * FFN;  // 2048*1024

    dispatch_stats<<<256, 256, 0, stream>>>(logits, dmax, drcp);
    combine_stats<<<8192, 256, 0, stream>>>(logits, cmax, crcp);

    // x_tilda[2048][1024] = dispatch^T @ x     (K=8192, A is K-major logits w/ exp staging)
    gemm_kernel<64, 128, 4, 8, 1, 0, false, false>
        <<<dim3(32, 8, 1), 256, 0, stream>>>(
            logits, x, xt, HID, BS, ES, HID, HID, 0, 0, 0, dmax, drcp);

    // h[e][128][2730] = silu(x_tilda[e] @ w_up[e])   (N bound 2730)
    gemm_kernel<128, 128, 8, 8, 0, 1, true, false>
        <<<dim3(1, 22, NEXP), 256, 0, stream>>>(
            xt, w_up, h, FFN, HID, HID, FFN, FFN,
            (long)SLOT * HID, (long)HID * FFN, (long)SLOT * FFN, nullptr, nullptr);

    // e_out[e][128][1024] = h[e] @ w_down[e]   (K bound 2730)
    gemm_kernel<128, 64, 8, 4, 0, 0, false, true>
        <<<dim3(1, 16, NEXP), 256, 0, stream>>>(
            h, w_down, eout, HID, FFN, FFN, HID, HID,
            (long)SLOT * FFN, (long)FFN * HID, (long)SLOT * HID, nullptr, nullptr);

    // y[8192][1024] = combine @ e_out   (A = exp(logits - cmax) staged, 1/csum epilogue)
    gemm_kernel<128, 128, 8, 8, 2, 2, false, false>
        <<<dim3(64, 8, 1), 256, 0, stream>>>(
            logits, eout, y, HID, ES, ES, HID, HID, 0, 0, 0, cmax, crcp);
}

// Round 2
// 1838.144 us; speedup vs baseline: 1.3069x; 1.3069x over previous
//
#include <hip/hip_runtime.h>
#include <hip/hip_bf16.h>
#include <math.h>

#define BS   8192   // batch*seq tokens
#define SEQQ 2048
#define HID  1024
#define ES   2048   // n_exp * slots
#define FFN  2730
#define FFNP 2752   // FFN padded to multiple of 32
#define NEXP 16
#define SLOT 128

typedef __attribute__((ext_vector_type(4))) float  f32x4;
typedef __attribute__((ext_vector_type(8))) short  short8;
typedef __attribute__((ext_vector_type(4))) short  short4v;

__device__ __forceinline__ short f2bf(float f) {
    union { float f; unsigned u; } v; v.f = f;
    unsigned r = v.u + 0x7fffu + ((v.u >> 16) & 1u);   // RNE
    return (short)(r >> 16);
}

// ---------------- softmax statistics kernels ----------------

__global__ __launch_bounds__(256) void dispatch_stats(const float* __restrict__ L,
                                                      float* __restrict__ dmax,
                                                      float* __restrict__ drcp)
{
    int b  = blockIdx.x >> 6;
    int c0 = (blockIdx.x & 63) * 32;
    int tc = threadIdx.x & 31;
    int rg = threadIdx.x >> 5;
    int c  = c0 + tc;
    const float* base = L + (size_t)b * SEQQ * ES + c;

    float mx = -1e30f;
    for (int r = rg; r < SEQQ; r += 8)
        mx = fmaxf(mx, base[(size_t)r * ES]);

    __shared__ float red[8][33];
    red[rg][tc] = mx;
    __syncthreads();
    if (rg == 0) {
        #pragma unroll
        for (int i = 1; i < 8; ++i) mx = fmaxf(mx, red[i][tc]);
        red[0][tc] = mx;
    }
    __syncthreads();
    mx = red[0][tc];
    __syncthreads();

    float s = 0.f;
    for (int r = rg; r < SEQQ; r += 8)
        s += __expf(base[(size_t)r * ES] - mx);
    red[rg][tc] = s;
    __syncthreads();
    if (rg == 0) {
        #pragma unroll
        for (int i = 1; i < 8; ++i) s += red[i][tc];
        dmax[b * ES + c] = mx;
        drcp[b * ES + c] = 1.f / s;
    }
}

__global__ __launch_bounds__(256) void combine_stats(const float* __restrict__ L,
                                                     float* __restrict__ cmax,
                                                     float* __restrict__ crcp)
{
    int t = blockIdx.x;
    const float* row = L + (size_t)t * ES;
    int tid = threadIdx.x;
    int wave = tid >> 6, lane = tid & 63;

    float mx = -1e30f;
    for (int i = tid; i < ES; i += 256) mx = fmaxf(mx, row[i]);
    #pragma unroll
    for (int off = 32; off > 0; off >>= 1) mx = fmaxf(mx, __shfl_down(mx, off, 64));
    __shared__ float sm[4];
    __shared__ float sbc;
    if (lane == 0) sm[wave] = mx;
    __syncthreads();
    if (tid == 0) sbc = fmaxf(fmaxf(sm[0], sm[1]), fmaxf(sm[2], sm[3]));
    __syncthreads();
    mx = sbc;

    float s = 0.f;
    for (int i = tid; i < ES; i += 256) s += __expf(row[i] - mx);
    #pragma unroll
    for (int off = 32; off > 0; off >>= 1) s += __shfl_down(s, off, 64);
    __syncthreads();
    if (lane == 0) sm[wave] = s;
    __syncthreads();
    if (tid == 0) {
        cmax[t] = mx;
        crcp[t] = 1.f / (sm[0] + sm[1] + sm[2] + sm[3]);
    }
}

// ---------------- bf16 MFMA GEMM ----------------
// C[M][N] = op(A) @ B, BK=32, 256 threads (4 waves, 2x2), mfma 16x16x32 bf16.
// AMODE 0: A row-major [M][K] (TA float or bf16-as-short)
// AMODE 1: A K-major [K][M]; elem = exp(A - aux0[b(k)*ES+m]) * aux1[b(k)*ES+m]
// AMODE 2: A row-major [M][K]; elem = exp(A - aux0[m])
// EPI 0: none; 1: silu; 2: scale row by aux1[m]
// NBND: bound N against Ndim (B staging + C store); KBND: bound K against Kdim (B staging only)
template<int BM, int BN, int AMODE, int EPI, bool NBND, bool KBND,
         typename TA, typename TB, typename TC>
__global__ __launch_bounds__(256, 2)
void mfma_gemm(const TA* __restrict__ A, const TB* __restrict__ B,
               TC* __restrict__ C, int Ndim, int Kdim,
               int lda, int ldb, int ldc,
               long sA, long sB, long sC,
               const float* __restrict__ aux0, const float* __restrict__ aux1)
{
    constexpr int BK = 32, LP = 40;   // row stride 40 shorts = 80B (16B-aligned, pad kills pow2 stride)
    A += (size_t)blockIdx.z * sA;
    B += (size_t)blockIdx.z * sB;
    C += (size_t)blockIdx.z * sC;
    const int m0 = blockIdx.x * BM;
    const int n0 = blockIdx.y * BN;
    const int tid  = threadIdx.x;
    const int lane = tid & 63;
    const int wid  = tid >> 6;
    const int wm = wid >> 1, wn = wid & 1;
    constexpr int WMT = BM / 2, WNT = BN / 2, MI = WMT / 16, NI = WNT / 16;

    __shared__ short As[BM][LP];
    __shared__ short Bs[BN][LP];

    f32x4 acc[MI][NI];
    #pragma unroll
    for (int mi = 0; mi < MI; ++mi)
        #pragma unroll
        for (int ni = 0; ni < NI; ++ni)
            acc[mi][ni] = (f32x4){0.f, 0.f, 0.f, 0.f};

    const int Kpad = KBND ? ((Kdim + 31) & ~31) : Kdim;

    for (int k0 = 0; k0 < Kpad; k0 += BK) {
        // ---- stage A ----
        if (AMODE == 1) {
            constexpr int PASSES = BM / 16;
            constexpr int KSTRIDE = 512 / BM;
            int mm  = tid % BM;
            int kpr = tid / BM;
            int m = m0 + mm;
            int bofs = (k0 >> 11) * ES;       // batch index (2048 % 32 == 0)
            float mx = aux0[bofs + m];
            float rs = aux1[bofs + m];
            #pragma unroll
            for (int p = 0; p < PASSES; ++p) {
                int kk = p * KSTRIDE + kpr * 2;
                float v0 = A[(size_t)(k0 + kk) * lda + m];
                float v1 = A[(size_t)(k0 + kk + 1) * lda + m];
                unsigned s0 = (unsigned short)f2bf(__expf(v0 - mx) * rs);
                unsigned s1 = (unsigned short)f2bf(__expf(v1 - mx) * rs);
                *reinterpret_cast<unsigned*>(&As[mm][kk]) = s0 | (s1 << 16);
            }
        } else {
            constexpr int PASSES = BM / 32;
            #pragma unroll
            for (int p = 0; p < PASSES; ++p) {
                int e  = p * 1024 + tid * 4;
                int mm = e >> 5;
                int kk = e & 31;
                const TA* ap = A + (size_t)(m0 + mm) * lda + k0 + kk;
                short4v sv;
                if constexpr (sizeof(TA) == 2) {
                    sv = *reinterpret_cast<const short4v*>(ap);
                } else {
                    f32x4 v = *reinterpret_cast<const f32x4*>(ap);
                    if (AMODE == 2) {
                        float mx = aux0[m0 + mm];
                        #pragma unroll
                        for (int j = 0; j < 4; ++j) v[j] = __expf(v[j] - mx);
                    }
                    #pragma unroll
                    for (int j = 0; j < 4; ++j) sv[j] = f2bf(v[j]);
                }
                *reinterpret_cast<short4v*>(&As[mm][kk]) = sv;
            }
        }
        // ---- stage B (global [K][N] -> Bs[n][k]) ----
        {
            constexpr int NSEG = 256 / BN;
            constexpr int SEG  = BK / NSEG;
            int nn = tid % BN;
            int ks = tid / BN;
            int n  = n0 + nn;
            bool nok = (!NBND) || (n < Ndim);
            short tmp[SEG];
            #pragma unroll
            for (int j = 0; j < SEG; ++j) {
                int k = k0 + ks * SEG + j;
                bool ok = nok && ((!KBND) || (k < Kdim));
                if constexpr (sizeof(TB) == 2) {
                    tmp[j] = ok ? B[(size_t)k * ldb + n] : (short)0;
                } else {
                    tmp[j] = ok ? f2bf(B[(size_t)k * ldb + n]) : (short)0;
                }
            }
            #pragma unroll
            for (int c = 0; c < SEG / 8; ++c) {
                short8 w;
                #pragma unroll
                for (int j = 0; j < 8; ++j) w[j] = tmp[c * 8 + j];
                *reinterpret_cast<short8*>(&Bs[nn][ks * SEG + c * 8]) = w;
            }
        }
        __syncthreads();

        // ---- fragments + MFMA ----
        {
            int ar = lane & 15;
            int ac = (lane >> 4) * 8;
            short8 af[MI], bf[NI];
            #pragma unroll
            for (int mi = 0; mi < MI; ++mi)
                af[mi] = *reinterpret_cast<const short8*>(&As[wm * WMT + mi * 16 + ar][ac]);
            #pragma unroll
            for (int ni = 0; ni < NI; ++ni)
                bf[ni] = *reinterpret_cast<const short8*>(&Bs[wn * WNT + ni * 16 + ar][ac]);
            #pragma unroll
            for (int mi = 0; mi < MI; ++mi)
                #pragma unroll
                for (int ni = 0; ni < NI; ++ni)
                    acc[mi][ni] = __builtin_amdgcn_mfma_f32_16x16x32_bf16(
                        af[mi], bf[ni], acc[mi][ni], 0, 0, 0);
        }
        __syncthreads();
    }

    // ---- epilogue ----
    #pragma unroll
    for (int mi = 0; mi < MI; ++mi) {
        #pragma unroll
        for (int ni = 0; ni < NI; ++ni) {
            int n = n0 + wn * WNT + ni * 16 + (lane & 15);
            if (NBND && n >= Ndim) continue;
            #pragma unroll
            for (int r = 0; r < 4; ++r) {
                int m = m0 + wm * WMT + mi * 16 + (lane >> 4) * 4 + r;
                float v = acc[mi][ni][r];
                if (EPI == 1)      v = v / (1.f + __expf(-v));   // silu
                else if (EPI == 2) v = v * aux1[m];              // 1/csum
                if constexpr (sizeof(TC) == 2) C[(size_t)m * ldc + n] = f2bf(v);
                else                           C[(size_t)m * ldc + n] = v;
            }
        }
    }
}

// ---------------- launch ----------------

extern "C" void kernel_launch(void* const* d_in, const int* in_sizes, int n_in,
                              void* d_out, int out_size, void* d_ws, size_t ws_size,
                              hipStream_t stream)
{
    const float* x      = (const float*)d_in[0];
    const float* logits = (const float*)d_in[1];   // [BS][ES]
    const float* w_up   = (const float*)d_in[2];   // [16][1024][2730]
    const float* w_down = (const float*)d_in[3];   // [16][2730][1024]
    float* y  = (float*)d_out;
    float* wsf = (float*)d_ws;

    float* dmax = wsf;                 // 4*2048
    float* drcp = wsf + 8192;
    float* cmax = wsf + 16384;         // 8192
    float* crcp = wsf + 24576;
    short* xt   = (short*)(wsf + 32768);                   // [2048][1024] bf16
    short* h    = xt + (size_t)2048 * 1024;                // [16][128][2752] bf16
    short* eout = h + (size_t)NEXP * SLOT * FFNP;          // [2048][1024] bf16

    // zero h (incl. K-pad columns 2730..2751) so GEMM3 needs no A-side bounds
    hipMemsetAsync(h, 0, (size_t)NEXP * SLOT * FFNP * sizeof(short), stream);

    dispatch_stats<<<256, 256, 0, stream>>>(logits, dmax, drcp);
    combine_stats<<<8192, 256, 0, stream>>>(logits, cmax, crcp);

    // xt[2048][1024] = dispatch^T @ x   (K=8192)
    mfma_gemm<128, 64, 1, 0, false, false, float, float, short>
        <<<dim3(16, 16, 1), 256, 0, stream>>>(
            logits, x, xt, HID, BS, ES, HID, HID, 0, 0, 0, dmax, drcp);

    // h[e][128][2752] = silu(xt_e @ w_up_e)   (N bound 2730)
    mfma_gemm<128, 128, 0, 1, true, false, short, float, short>
        <<<dim3(1, 22, NEXP), 256, 0, stream>>>(
            xt, w_up, h, FFN, HID, HID, FFN, FFNP,
            (long)SLOT * HID, (long)HID * FFN, (long)SLOT * FFNP, nullptr, nullptr);

    // eout[e][128][1024] = h_e @ w_down_e   (K bound 2730 on B; A padded to 2752)
    mfma_gemm<64, 128, 0, 0, false, true, short, float, short>
        <<<dim3(2, 8, NEXP), 256, 0, stream>>>(
            h, w_down, eout, HID, FFN, FFNP, HID, HID,
            (long)SLOT * FFNP, (long)FFN * HID, (long)SLOT * HID, nullptr, nullptr);

    // y[8192][1024] = combine @ eout   (K=2048)
    mfma_gemm<128, 128, 2, 2, false, false, float, short, float>
        <<<dim3(64, 8, 1), 256, 0, stream>>>(
            logits, eout, y, HID, ES, ES, HID, HID, 0, 0, 0, cmax, crcp);
}

// Round 3
// 780.470 us; speedup vs baseline: 3.0781x; 2.3552x over previous
//
#include <hip/hip_runtime.h>
#include <hip/hip_bf16.h>
#include <math.h>

#define BS   8192   // batch*seq tokens
#define SEQQ 2048
#define HID  1024
#define ES   2048   // n_exp * slots
#define FFN  2730
#define FFNP 2752   // FFN padded to multiple of 32
#define NEXP 16
#define SLOT 128

typedef __attribute__((ext_vector_type(4))) float  f32x4;
typedef __attribute__((ext_vector_type(2))) float  f32x2;
typedef __attribute__((ext_vector_type(8))) short  short8;
typedef __attribute__((ext_vector_type(4))) short  short4v;

__device__ __forceinline__ short f2bf(float f) {
    union { float f; unsigned u; } v; v.f = f;
    unsigned r = v.u + 0x7fffu + ((v.u >> 16) & 1u);   // RNE
    return (short)(r >> 16);
}

// ---------------- softmax statistics kernels ----------------

__global__ __launch_bounds__(256) void dispatch_stats(const float* __restrict__ L,
                                                      float* __restrict__ dmax,
                                                      float* __restrict__ drcp)
{
    int b  = blockIdx.x >> 6;
    int c0 = (blockIdx.x & 63) * 32;
    int tc = threadIdx.x & 31;
    int rg = threadIdx.x >> 5;
    int c  = c0 + tc;
    const float* base = L + (size_t)b * SEQQ * ES + c;

    float mx = -1e30f;
    for (int r = rg; r < SEQQ; r += 8)
        mx = fmaxf(mx, base[(size_t)r * ES]);

    __shared__ float red[8][33];
    red[rg][tc] = mx;
    __syncthreads();
    if (rg == 0) {
        #pragma unroll
        for (int i = 1; i < 8; ++i) mx = fmaxf(mx, red[i][tc]);
        red[0][tc] = mx;
    }
    __syncthreads();
    mx = red[0][tc];
    __syncthreads();

    float s = 0.f;
    for (int r = rg; r < SEQQ; r += 8)
        s += __expf(base[(size_t)r * ES] - mx);
    red[rg][tc] = s;
    __syncthreads();
    if (rg == 0) {
        #pragma unroll
        for (int i = 1; i < 8; ++i) s += red[i][tc];
        dmax[b * ES + c] = mx;
        drcp[b * ES + c] = 1.f / s;
    }
}

__global__ __launch_bounds__(256) void combine_stats(const float* __restrict__ L,
                                                     float* __restrict__ cmax,
                                                     float* __restrict__ crcp)
{
    int t = blockIdx.x;
    const float* row = L + (size_t)t * ES;
    int tid = threadIdx.x;
    int wave = tid >> 6, lane = tid & 63;

    float mx = -1e30f;
    for (int i = tid; i < ES; i += 256) mx = fmaxf(mx, row[i]);
    #pragma unroll
    for (int off = 32; off > 0; off >>= 1) mx = fmaxf(mx, __shfl_down(mx, off, 64));
    __shared__ float sm[4];
    __shared__ float sbc;
    if (lane == 0) sm[wave] = mx;
    __syncthreads();
    if (tid == 0) sbc = fmaxf(fmaxf(sm[0], sm[1]), fmaxf(sm[2], sm[3]));
    __syncthreads();
    mx = sbc;

    float s = 0.f;
    for (int i = tid; i < ES; i += 256) s += __expf(row[i] - mx);
    #pragma unroll
    for (int off = 32; off > 0; off >>= 1) s += __shfl_down(s, off, 64);
    __syncthreads();
    if (lane == 0) sm[wave] = s;
    __syncthreads();
    if (tid == 0) {
        cmax[t] = mx;
        crcp[t] = 1.f / (sm[0] + sm[1] + sm[2] + sm[3]);
    }
}

// ---------------- bf16 MFMA GEMM (vectorized staging) ----------------
// C[M][N] = op(A) @ B, BK=32, 256 threads (4 waves, 2x2), mfma 16x16x32 bf16.
// AMODE 0: A row-major [M][K]
// AMODE 1: A K-major [K][M] (BM must be 64); elem = exp(A-aux0[b(k)*ES+m])*aux1[b(k)*ES+m]
// AMODE 2: A row-major [M][K] float; elem = exp(A - aux0[m])
// EPI 0 none; 1 silu; 2 scale row by aux1[m]
// NBND: bound N (B staging + C store). KBND: bound K on B rows (A must be K-padded).
// BT:   B stored [N][K] k-contiguous bf16 (transposed). Else B is [K][N] float, BN==64.
// CT:   write C transposed: C[n*ldc + m] (bf16, vectorized over the 4 acc rows).
// UNAL: float-B rows only 8B-aligned (use f32x2 loads) — w_up's ldb=2730.
template<int BM, int BN, int AMODE, int EPI, bool NBND, bool KBND, bool BT, bool CT, bool UNAL,
         typename TA, typename TB, typename TC>
__global__ __launch_bounds__(256)
void mfma_gemm(const TA* __restrict__ A, const TB* __restrict__ B,
               TC* __restrict__ C, int Ndim, int Kdim,
               int lda, int ldb, int ldc,
               long sA, long sB, long sC,
               const float* __restrict__ aux0, const float* __restrict__ aux1)
{
    constexpr int BK = 32, LP = 40;   // 80B rows: 16B-aligned, non-pow2 bank stride
    A += (size_t)blockIdx.z * sA;
    B += (size_t)blockIdx.z * sB;
    C += (size_t)blockIdx.z * sC;
    const int m0 = blockIdx.x * BM;
    const int n0 = blockIdx.y * BN;
    const int tid  = threadIdx.x;
    const int lane = tid & 63;
    const int wid  = tid >> 6;
    const int wm = wid >> 1, wn = wid & 1;
    constexpr int WMT = BM / 2, WNT = BN / 2, MI = WMT / 16, NI = WNT / 16;

    __shared__ short As[BM][LP];
    __shared__ short Bs[BN][LP];

    f32x4 acc[MI][NI];
    #pragma unroll
    for (int mi = 0; mi < MI; ++mi)
        #pragma unroll
        for (int ni = 0; ni < NI; ++ni)
            acc[mi][ni] = (f32x4){0.f, 0.f, 0.f, 0.f};

    const int Kloop = KBND ? ((Kdim + 31) & ~31) : Kdim;

    for (int k0 = 0; k0 < Kloop; k0 += BK) {
        // ---------- stage A ----------
        if constexpr (AMODE == 1) {
            // BM == 64: 4 m x 2 k per thread, vector loads along m
            const int mm4 = (tid & 15) * 4;
            const int kk2 = (tid >> 4) * 2;
            const int m   = m0 + mm4;
            const int bofs = (k0 >> 11) * ES;   // batch of this K-step (2048%32==0)
            f32x4 mx = *reinterpret_cast<const f32x4*>(&aux0[bofs + m]);
            f32x4 rs = *reinterpret_cast<const f32x4*>(&aux1[bofs + m]);
            f32x4 v0 = *reinterpret_cast<const f32x4*>(&A[(size_t)(k0 + kk2) * lda + m]);
            f32x4 v1 = *reinterpret_cast<const f32x4*>(&A[(size_t)(k0 + kk2 + 1) * lda + m]);
            #pragma unroll
            for (int i = 0; i < 4; ++i) {
                unsigned lo = (unsigned short)f2bf(__expf(v0[i] - mx[i]) * rs[i]);
                unsigned hi = (unsigned short)f2bf(__expf(v1[i] - mx[i]) * rs[i]);
                *reinterpret_cast<unsigned*>(&As[mm4 + i][kk2]) = lo | (hi << 16);
            }
        } else if constexpr (sizeof(TA) == 2) {
            // bf16 row-major: KCH k's per thread, short8 loads
            constexpr int KCH = 32 / (256 / BM);
            const int mm = tid % BM;
            const int kg = (tid / BM) * KCH;
            #pragma unroll
            for (int j = 0; j < KCH / 8; ++j) {
                short8 v = *reinterpret_cast<const short8*>(&A[(size_t)(m0 + mm) * lda + k0 + kg + 8 * j]);
                *reinterpret_cast<short4v*>(&As[mm][kg + 8 * j])     = (short4v){v[0], v[1], v[2], v[3]};
                *reinterpret_cast<short4v*>(&As[mm][kg + 8 * j + 4]) = (short4v){v[4], v[5], v[6], v[7]};
            }
        } else {
            // float row-major (AMODE 0 or 2): f32x4 loads
            constexpr int KCH = 32 / (256 / BM);
            const int mm = tid % BM;
            const int kg = (tid / BM) * KCH;
            float mx = (AMODE == 2) ? aux0[m0 + mm] : 0.f;
            #pragma unroll
            for (int j = 0; j < KCH / 4; ++j) {
                f32x4 v = *reinterpret_cast<const f32x4*>(&A[(size_t)(m0 + mm) * lda + k0 + kg + 4 * j]);
                if (AMODE == 2) {
                    #pragma unroll
                    for (int i = 0; i < 4; ++i) v[i] = __expf(v[i] - mx);
                }
                short4v s = (short4v){f2bf(v[0]), f2bf(v[1]), f2bf(v[2]), f2bf(v[3])};
                *reinterpret_cast<short4v*>(&As[mm][kg + 4 * j]) = s;
            }
        }
        // ---------- stage B ----------
        if constexpr (BT) {
            // bf16 [N][K] k-contiguous
            constexpr int KCH = 32 / (256 / BN);
            const int nn = tid % BN;
            const int kg = (tid / BN) * KCH;
            #pragma unroll
            for (int j = 0; j < KCH / 8; ++j) {
                short8 v = *reinterpret_cast<const short8*>(&B[(size_t)(n0 + nn) * ldb + k0 + kg + 8 * j]);
                *reinterpret_cast<short4v*>(&Bs[nn][kg + 8 * j])     = (short4v){v[0], v[1], v[2], v[3]};
                *reinterpret_cast<short4v*>(&Bs[nn][kg + 8 * j + 4]) = (short4v){v[4], v[5], v[6], v[7]};
            }
        } else {
            // float [K][N], BN == 64: 4 n x 2 k per thread
            const int nn4 = (tid & 15) * 4;
            const int kk2 = (tid >> 4) * 2;
            const int n   = n0 + nn4;
            float vv[2][4];
            #pragma unroll
            for (int r = 0; r < 2; ++r) {
                int k = k0 + kk2 + r;
                bool kok = (!KBND) || (k < Kdim);
                if constexpr (UNAL) {
                    f32x2 a = (kok && (!NBND || n     < Ndim)) ? *reinterpret_cast<const f32x2*>(&B[(size_t)k * ldb + n])     : (f32x2){0.f, 0.f};
                    f32x2 b = (kok && (!NBND || n + 2 < Ndim)) ? *reinterpret_cast<const f32x2*>(&B[(size_t)k * ldb + n + 2]) : (f32x2){0.f, 0.f};
                    vv[r][0] = a[0]; vv[r][1] = a[1]; vv[r][2] = b[0]; vv[r][3] = b[1];
                } else {
                    f32x4 v = kok ? *reinterpret_cast<const f32x4*>(&B[(size_t)k * ldb + n]) : (f32x4){0.f, 0.f, 0.f, 0.f};
                    #pragma unroll
                    for (int i = 0; i < 4; ++i) vv[r][i] = v[i];
                }
            }
            #pragma unroll
            for (int i = 0; i < 4; ++i) {
                unsigned lo = (unsigned short)f2bf(vv[0][i]);
                unsigned hi = (unsigned short)f2bf(vv[1][i]);
                *reinterpret_cast<unsigned*>(&Bs[nn4 + i][kk2]) = lo | (hi << 16);
            }
        }
        __syncthreads();

        // ---------- fragments + MFMA ----------
        {
            const int ar = lane & 15;
            const int ac = (lane >> 4) * 8;
            short8 af[MI], bf[NI];
            #pragma unroll
            for (int mi = 0; mi < MI; ++mi)
                af[mi] = *reinterpret_cast<const short8*>(&As[wm * WMT + mi * 16 + ar][ac]);
            #pragma unroll
            for (int ni = 0; ni < NI; ++ni)
                bf[ni] = *reinterpret_cast<const short8*>(&Bs[wn * WNT + ni * 16 + ar][ac]);
            #pragma unroll
            for (int mi = 0; mi < MI; ++mi)
                #pragma unroll
                for (int ni = 0; ni < NI; ++ni)
                    acc[mi][ni] = __builtin_amdgcn_mfma_f32_16x16x32_bf16(
                        af[mi], bf[ni], acc[mi][ni], 0, 0, 0);
        }
        __syncthreads();
    }

    // ---------- epilogue ----------
    #pragma unroll
    for (int mi = 0; mi < MI; ++mi) {
        #pragma unroll
        for (int ni = 0; ni < NI; ++ni) {
            const int n = n0 + wn * WNT + ni * 16 + (lane & 15);
            if (NBND && n >= Ndim) continue;
            const int mbase = m0 + wm * WMT + mi * 16 + (lane >> 4) * 4;
            if constexpr (CT) {
                short4v s;
                #pragma unroll
                for (int r = 0; r < 4; ++r) s[r] = f2bf(acc[mi][ni][r]);
                *reinterpret_cast<short4v*>(&C[(size_t)n * ldc + mbase]) = s;
            } else {
                #pragma unroll
                for (int r = 0; r < 4; ++r) {
                    float v = acc[mi][ni][r];
                    if (EPI == 1)      v = v / (1.f + __expf(-v));   // silu
                    else if (EPI == 2) v = v * aux1[mbase + r];      // 1/csum
                    if constexpr (sizeof(TC) == 2) C[(size_t)(mbase + r) * ldc + n] = f2bf(v);
                    else                           C[(size_t)(mbase + r) * ldc + n] = v;
                }
            }
        }
    }
}

// ---------------- launch ----------------

extern "C" void kernel_launch(void* const* d_in, const int* in_sizes, int n_in,
                              void* d_out, int out_size, void* d_ws, size_t ws_size,
                              hipStream_t stream)
{
    const float* x      = (const float*)d_in[0];
    const float* logits = (const float*)d_in[1];   // [BS][ES]
    const float* w_up   = (const float*)d_in[2];   // [16][1024][2730]
    const float* w_down = (const float*)d_in[3];   // [16][2730][1024]
    float* y  = (float*)d_out;
    float* wsf = (float*)d_ws;

    float* dmax = wsf;                 // 4*2048
    float* drcp = wsf + 8192;
    float* cmax = wsf + 16384;         // 8192
    float* crcp = wsf + 24576;
    short* xt    = (short*)(wsf + 32768);                  // [2048][1024] bf16
    short* h     = xt + (size_t)2048 * 1024;               // [16][128][2752] bf16
    short* eoutT = h + (size_t)NEXP * SLOT * FFNP;         // [1024][2048] bf16 (transposed)

    // zero h pad columns (2730..2751) so GEMM3's A needs no K bound
    hipMemsetAsync(h, 0, (size_t)NEXP * SLOT * FFNP * sizeof(short), stream);

    dispatch_stats<<<256, 256, 0, stream>>>(logits, dmax, drcp);
    combine_stats<<<8192, 256, 0, stream>>>(logits, cmax, crcp);

    // G1: xt[2048][1024] = dispatch^T @ x   (K=8192)
    mfma_gemm<64, 64, 1, 0, false, false, false, false, false, float, float, short>
        <<<dim3(32, 16, 1), 256, 0, stream>>>(
            logits, x, xt, HID, BS, ES, HID, HID, 0, 0, 0, dmax, drcp);

    // G2: h[e][128][2752] = silu(xt_e @ w_up_e)   (N bound 2730, unaligned B rows)
    mfma_gemm<128, 64, 0, 1, true, false, false, false, true, short, float, short>
        <<<dim3(1, 43, NEXP), 256, 0, stream>>>(
            xt, w_up, h, FFN, HID, HID, FFN, FFNP,
            (long)SLOT * HID, (long)HID * FFN, (long)SLOT * FFNP, nullptr, nullptr);

    // G3: eoutT[:, e*128+m] = (h_e @ w_down_e)^T   (K bound 2730 on B; A K-padded; C transposed)
    mfma_gemm<64, 64, 0, 0, false, true, false, true, false, short, float, short>
        <<<dim3(2, 16, NEXP), 256, 0, stream>>>(
            h, w_down, eoutT, HID, FFN, FFNP, HID, ES,
            (long)SLOT * FFNP, (long)FFN * HID, (long)SLOT, nullptr, nullptr);

    // G4: y[8192][1024] = combine @ eout   (B = eoutT, k-contiguous bf16)
    mfma_gemm<128, 128, 2, 2, false, false, true, false, false, float, short, float>
        <<<dim3(64, 8, 1), 256, 0, stream>>>(
            logits, eoutT, y, HID, ES, ES, ES, HID, 0, 0, 0, cmax, crcp);
}

// Round 4
// 646.192 us; speedup vs baseline: 3.7177x; 1.2078x over previous
//
#include <hip/hip_runtime.h>
#include <hip/hip_bf16.h>
#include <math.h>

#define BS   8192   // batch*seq tokens
#define SEQQ 2048
#define HID  1024
#define ES   2048   // n_exp * slots
#define FFN  2730
#define FFNP 2752   // FFN padded to multiple of 32
#define NEXP 16
#define SLOT 128

typedef __attribute__((ext_vector_type(4))) float  f32x4;
typedef __attribute__((ext_vector_type(8))) short  short8;
typedef __attribute__((ext_vector_type(4))) short  short4v;

__device__ __forceinline__ short f2bf(float f) {
    union { float f; unsigned u; } v; v.f = f;
    unsigned r = v.u + 0x7fffu + ((v.u >> 16) & 1u);   // RNE
    return (short)(r >> 16);
}

// Swizzled LDS index (shorts). Row = 32 shorts = 64B. 16B slot swizzle:
// slot' = slot ^ ((row>>1)&3). Spreads fragment reads and 16B staging writes
// uniformly over all 8 bank groups (BW floor, conflict-free).
__device__ __forceinline__ int swz(int row, int kk) {
    return (row << 5) + ((((kk >> 3) ^ (row >> 1)) & 3) << 3) + (kk & 7);
}

// ---------------- prep: dispatch softmax -> DT bf16 [ES][BS] ----------------
// Column softmax over seq per batch; writes normalized bf16 transposed.
__global__ __launch_bounds__(512) void dispatch_kernel(const float* __restrict__ L,
                                                       short* __restrict__ DT)
{
    const int b  = blockIdx.x >> 6;
    const int c0 = (blockIdx.x & 63) * 32;
    const int tc = threadIdx.x & 31;    // column within tile
    const int rg = threadIdx.x >> 5;    // 0..15 row group
    const int c  = c0 + tc;
    const float* base = L + (size_t)b * SEQQ * ES + c;

    __shared__ float red[16][33];

    float mx = -1e30f;
    for (int r = rg; r < SEQQ; r += 16)
        mx = fmaxf(mx, base[(size_t)r * ES]);
    red[rg][tc] = mx;
    __syncthreads();
    if (rg == 0) {
        #pragma unroll
        for (int i = 1; i < 16; ++i) mx = fmaxf(mx, red[i][tc]);
        red[0][tc] = mx;
    }
    __syncthreads();
    mx = red[0][tc];
    __syncthreads();

    float s = 0.f;
    for (int r = rg; r < SEQQ; r += 16)
        s += __expf(base[(size_t)r * ES] - mx);
    red[rg][tc] = s;
    __syncthreads();
    if (rg == 0) {
        #pragma unroll
        for (int i = 1; i < 16; ++i) s += red[i][tc];
        red[0][tc] = 1.f / s;
    }
    __syncthreads();
    const float rcp = red[0][tc];
    __syncthreads();

    __shared__ short T[32][264];   // 264-short rows: 16B-aligned segs, odd bank stride
    for (int chunk = 0; chunk < SEQQ / 256; ++chunk) {
        #pragma unroll
        for (int j = 0; j < 16; ++j) {
            int r = chunk * 256 + rg * 16 + j;
            float v = base[(size_t)r * ES];
            T[tc][rg * 16 + j] = f2bf(__expf(v - mx) * rcp);
        }
        __syncthreads();
        {
            const int row = threadIdx.x >> 4;   // 0..31
            const int seg = threadIdx.x & 15;   // 0..15
            short8 w0 = *reinterpret_cast<const short8*>(&T[row][seg * 16]);
            short8 w1 = *reinterpret_cast<const short8*>(&T[row][seg * 16 + 8]);
            size_t o = (size_t)(c0 + row) * BS + (size_t)b * SEQQ + chunk * 256 + seg * 16;
            *reinterpret_cast<short8*>(&DT[o])     = w0;
            *reinterpret_cast<short8*>(&DT[o + 8]) = w1;
        }
        __syncthreads();
    }
}

// ---------------- prep: combine softmax -> CB bf16 [BS][ES] ----------------
__global__ __launch_bounds__(256) void combine_kernel(const float* __restrict__ L,
                                                      short* __restrict__ CB)
{
    const int t = blockIdx.x;
    const float* row = L + (size_t)t * ES;
    const int tid = threadIdx.x;
    const int wave = tid >> 6, lane = tid & 63;

    f32x4 a = *reinterpret_cast<const f32x4*>(&row[tid * 8]);
    f32x4 b = *reinterpret_cast<const f32x4*>(&row[tid * 8 + 4]);

    float mx = fmaxf(fmaxf(fmaxf(a[0], a[1]), fmaxf(a[2], a[3])),
                     fmaxf(fmaxf(b[0], b[1]), fmaxf(b[2], b[3])));
    #pragma unroll
    for (int off = 32; off > 0; off >>= 1) mx = fmaxf(mx, __shfl_down(mx, off, 64));
    __shared__ float sm[4];
    __shared__ float sbc;
    if (lane == 0) sm[wave] = mx;
    __syncthreads();
    if (tid == 0) sbc = fmaxf(fmaxf(sm[0], sm[1]), fmaxf(sm[2], sm[3]));
    __syncthreads();
    mx = sbc;
    __syncthreads();

    float e[8];
    #pragma unroll
    for (int j = 0; j < 4; ++j) e[j]     = __expf(a[j] - mx);
    #pragma unroll
    for (int j = 0; j < 4; ++j) e[4 + j] = __expf(b[j] - mx);
    float s = 0.f;
    #pragma unroll
    for (int j = 0; j < 8; ++j) s += e[j];
    #pragma unroll
    for (int off = 32; off > 0; off >>= 1) s += __shfl_down(s, off, 64);
    if (lane == 0) sm[wave] = s;
    __syncthreads();
    if (tid == 0) sbc = 1.f / (sm[0] + sm[1] + sm[2] + sm[3]);
    __syncthreads();
    const float rcp = sbc;

    short8 w;
    #pragma unroll
    for (int j = 0; j < 8; ++j) w[j] = f2bf(e[j] * rcp);
    *reinterpret_cast<short8*>(&CB[(size_t)t * ES + tid * 8]) = w;
}

// ---------------- bf16 MFMA GEMM (swizzled LDS) ----------------
// C[M][N] = A @ B. A: bf16 row-major [M][K]. BK=32, 256 threads, 4 waves 2x2.
// BT:  B bf16 [N][K] k-contiguous. Else B float [K][N], BN must be 64.
// EPI: 0 none, 1 silu. NBND: bound N. KBND: bound K on B (A must be K-padded).
// CT:  write C transposed (C[n*ldc + m], bf16 short4v).
template<int BM, int BN, int EPI, bool NBND, bool KBND, bool BT, bool CT,
         typename TB, typename TC>
__global__ __launch_bounds__(256)
void mfma_gemm(const short* __restrict__ A, const TB* __restrict__ B,
               TC* __restrict__ C, int Ndim, int Kdim,
               int lda, int ldb, int ldc,
               long sA, long sB, long sC)
{
    constexpr int BK = 32;
    A += (size_t)blockIdx.z * sA;
    B += (size_t)blockIdx.z * sB;
    C += (size_t)blockIdx.z * sC;
    const int m0 = blockIdx.x * BM;
    const int n0 = blockIdx.y * BN;
    const int tid  = threadIdx.x;
    const int lane = tid & 63;
    const int wid  = tid >> 6;
    const int wm = wid >> 1, wn = wid & 1;
    constexpr int WMT = BM / 2, WNT = BN / 2, MI = WMT / 16, NI = WNT / 16;

    __shared__ short As[BM * 32];
    __shared__ short Bs[BN * 32];

    f32x4 acc[MI][NI];
    #pragma unroll
    for (int mi = 0; mi < MI; ++mi)
        #pragma unroll
        for (int ni = 0; ni < NI; ++ni)
            acc[mi][ni] = (f32x4){0.f, 0.f, 0.f, 0.f};

    const int Kloop = KBND ? ((Kdim + 31) & ~31) : Kdim;

    for (int k0 = 0; k0 < Kloop; k0 += BK) {
        // ---- stage A (bf16 row-major, short8 -> swizzled 16B writes) ----
        {
            constexpr int KCH = 32 / (256 / BM);     // BM=128 -> 16
            const int mm = tid % BM;
            const int kg = (tid / BM) * KCH;
            #pragma unroll
            for (int j = 0; j < KCH / 8; ++j) {
                short8 v = *reinterpret_cast<const short8*>(
                    &A[(size_t)(m0 + mm) * lda + k0 + kg + 8 * j]);
                *reinterpret_cast<short8*>(&As[swz(mm, kg + 8 * j)]) = v;
            }
        }
        // ---- stage B ----
        if constexpr (BT) {
            constexpr int KCH = 32 / (256 / BN);
            const int nn = tid % BN;
            const int kg = (tid / BN) * KCH;
            #pragma unroll
            for (int j = 0; j < KCH / 8; ++j) {
                short8 v = *reinterpret_cast<const short8*>(
                    &B[(size_t)(n0 + nn) * ldb + k0 + kg + 8 * j]);
                *reinterpret_cast<short8*>(&Bs[swz(nn, kg + 8 * j)]) = v;
            }
        } else {
            static_assert(BT || BN == 64, "float-B path requires BN==64");
            const int nn = tid & 63;
            const int s  = tid >> 6;             // k-slot 0..3
            const int n  = n0 + nn;
            const bool nok = (!NBND) || (n < Ndim);
            short8 w;
            #pragma unroll
            for (int j = 0; j < 8; ++j) {
                int k = k0 + s * 8 + j;
                bool ok = nok && ((!KBND) || (k < Kdim));
                float v = ok ? B[(size_t)k * ldb + n] : 0.f;
                w[j] = f2bf(v);
            }
            *reinterpret_cast<short8*>(&Bs[swz(nn, s * 8)]) = w;
        }
        __syncthreads();

        // ---- fragments + MFMA ----
        {
            const int ar = lane & 15;
            const int ac = (lane >> 4) * 8;
            short8 af[MI], bf[NI];
            #pragma unroll
            for (int mi = 0; mi < MI; ++mi)
                af[mi] = *reinterpret_cast<const short8*>(&As[swz(wm * WMT + mi * 16 + ar, ac)]);
            #pragma unroll
            for (int ni = 0; ni < NI; ++ni)
                bf[ni] = *reinterpret_cast<const short8*>(&Bs[swz(wn * WNT + ni * 16 + ar, ac)]);
            #pragma unroll
            for (int mi = 0; mi < MI; ++mi)
                #pragma unroll
                for (int ni = 0; ni < NI; ++ni)
                    acc[mi][ni] = __builtin_amdgcn_mfma_f32_16x16x32_bf16(
                        af[mi], bf[ni], acc[mi][ni], 0, 0, 0);
        }
        __syncthreads();
    }

    // ---- epilogue ----
    #pragma unroll
    for (int mi = 0; mi < MI; ++mi) {
        #pragma unroll
        for (int ni = 0; ni < NI; ++ni) {
            const int n = n0 + wn * WNT + ni * 16 + (lane & 15);
            if (NBND && n >= Ndim) continue;
            const int mbase = m0 + wm * WMT + mi * 16 + (lane >> 4) * 4;
            if constexpr (CT) {
                short4v sv;
                #pragma unroll
                for (int r = 0; r < 4; ++r) sv[r] = f2bf(acc[mi][ni][r]);
                *reinterpret_cast<short4v*>(&C[(size_t)n * ldc + mbase]) = sv;
            } else {
                #pragma unroll
                for (int r = 0; r < 4; ++r) {
                    float v = acc[mi][ni][r];
                    if (EPI == 1) v = v / (1.f + __expf(-v));   // silu
                    if constexpr (sizeof(TC) == 2) C[(size_t)(mbase + r) * ldc + n] = f2bf(v);
                    else                           C[(size_t)(mbase + r) * ldc + n] = v;
                }
            }
        }
    }
}

// ---------------- launch ----------------

extern "C" void kernel_launch(void* const* d_in, const int* in_sizes, int n_in,
                              void* d_out, int out_size, void* d_ws, size_t ws_size,
                              hipStream_t stream)
{
    const float* x      = (const float*)d_in[0];
    const float* logits = (const float*)d_in[1];   // [BS][ES]
    const float* w_up   = (const float*)d_in[2];   // [16][1024][2730]
    const float* w_down = (const float*)d_in[3];   // [16][2730][1024]
    float* y = (float*)d_out;

    short* DT    = (short*)((float*)d_ws + 32768);          // [2048][8192] bf16, normalized dispatch^T
    short* CB    = DT + (size_t)ES * BS;                    // [8192][2048] bf16, normalized combine
    short* xt    = CB + (size_t)BS * ES;                    // [2048][1024] bf16
    short* h     = xt + (size_t)ES * HID;                   // [16][128][2752] bf16
    short* eoutT = h + (size_t)NEXP * SLOT * FFNP;          // [1024][2048] bf16 (transposed)

    // zero h (pad cols 2730..2751 must be 0 for G3's K-padded A)
    hipMemsetAsync(h, 0, (size_t)NEXP * SLOT * FFNP * sizeof(short), stream);

    dispatch_kernel<<<256, 512, 0, stream>>>(logits, DT);
    combine_kernel<<<8192, 256, 0, stream>>>(logits, CB);

    // G1: xt[2048][1024] = DT @ x   (K=8192; A bf16, B float [K][N])
    mfma_gemm<128, 64, 0, false, false, false, false, float, short>
        <<<dim3(16, 16, 1), 256, 0, stream>>>(
            DT, x, xt, HID, BS, BS, HID, HID, 0, 0, 0);

    // G2: h[e][128][2752] = silu(xt_e @ w_up_e)   (N bound 2730)
    mfma_gemm<128, 64, 1, true, false, false, false, float, short>
        <<<dim3(1, 43, NEXP), 256, 0, stream>>>(
            xt, w_up, h, FFN, HID, HID, FFN, FFNP,
            (long)SLOT * HID, (long)HID * FFN, (long)SLOT * FFNP);

    // G3: eoutT[n][e*128+m] = (h_e @ w_down_e)^T   (K bound 2730 on B; A K-padded; CT)
    mfma_gemm<128, 64, 0, false, true, false, true, float, short>
        <<<dim3(1, 16, NEXP), 256, 0, stream>>>(
            h, w_down, eoutT, HID, FFN, FFNP, HID, ES,
            (long)SLOT * FFNP, (long)FFN * HID, (long)SLOT);

    // G4: y[8192][1024] = CB @ eout   (A bf16 rm, B = eoutT bf16 [N][K])
    mfma_gemm<128, 128, 0, false, false, true, false, short, float>
        <<<dim3(64, 8, 1), 256, 0, stream>>>(
            CB, eoutT, y, HID, ES, ES, ES, HID, 0, 0, 0);
}

// Round 5
// 506.824 us; speedup vs baseline: 4.7400x; 1.2750x over previous
//
#include <hip/hip_runtime.h>
#include <hip/hip_bf16.h>
#include <math.h>

#define BS   8192   // batch*seq tokens
#define SEQQ 2048
#define HID  1024
#define ES   2048   // n_exp * slots
#define FFN  2730
#define FFNP 2752   // FFN padded to multiple of 32
#define NEXP 16
#define SLOT 128

typedef __attribute__((ext_vector_type(4))) float  f32x4;
typedef __attribute__((ext_vector_type(8))) short  short8;
typedef __attribute__((ext_vector_type(4))) short  short4v;

__device__ __forceinline__ short f2bf(float f) {
    union { float f; unsigned u; } v; v.f = f;
    unsigned r = v.u + 0x7fffu + ((v.u >> 16) & 1u);   // RNE
    return (short)(r >> 16);
}

// Swizzled LDS index (shorts). Row = 32 shorts = 64B. 16B slot swizzle:
// slot' = slot ^ ((row>>1)&3). Conflict-free for both 16B staging writes and
// fragment ds_read_b128 (verified round 4: SQ_LDS_BANK_CONFLICT == 0).
__device__ __forceinline__ int swz(int row, int kk) {
    return (row << 5) + ((((kk >> 3) ^ (row >> 1)) & 3) << 3) + (kk & 7);
}

// ---------------- prep: dispatch softmax -> DT bf16 [ES][BS] ----------------
__global__ __launch_bounds__(512) void dispatch_kernel(const float* __restrict__ L,
                                                       short* __restrict__ DT)
{
    const int b  = blockIdx.x >> 6;
    const int c0 = (blockIdx.x & 63) * 32;
    const int tc = threadIdx.x & 31;    // column within tile
    const int rg = threadIdx.x >> 5;    // 0..15 row group
    const int c  = c0 + tc;
    const float* base = L + (size_t)b * SEQQ * ES + c;

    __shared__ float red[16][33];

    float mx = -1e30f;
    for (int r = rg; r < SEQQ; r += 16)
        mx = fmaxf(mx, base[(size_t)r * ES]);
    red[rg][tc] = mx;
    __syncthreads();
    if (rg == 0) {
        #pragma unroll
        for (int i = 1; i < 16; ++i) mx = fmaxf(mx, red[i][tc]);
        red[0][tc] = mx;
    }
    __syncthreads();
    mx = red[0][tc];
    __syncthreads();

    float s = 0.f;
    for (int r = rg; r < SEQQ; r += 16)
        s += __expf(base[(size_t)r * ES] - mx);
    red[rg][tc] = s;
    __syncthreads();
    if (rg == 0) {
        #pragma unroll
        for (int i = 1; i < 16; ++i) s += red[i][tc];
        red[0][tc] = 1.f / s;
    }
    __syncthreads();
    const float rcp = red[0][tc];
    __syncthreads();

    __shared__ short T[32][264];
    for (int chunk = 0; chunk < SEQQ / 256; ++chunk) {
        #pragma unroll
        for (int j = 0; j < 16; ++j) {
            int r = chunk * 256 + rg * 16 + j;
            float v = base[(size_t)r * ES];
            T[tc][rg * 16 + j] = f2bf(__expf(v - mx) * rcp);
        }
        __syncthreads();
        {
            const int row = threadIdx.x >> 4;
            const int seg = threadIdx.x & 15;
            short8 w0 = *reinterpret_cast<const short8*>(&T[row][seg * 16]);
            short8 w1 = *reinterpret_cast<const short8*>(&T[row][seg * 16 + 8]);
            size_t o = (size_t)(c0 + row) * BS + (size_t)b * SEQQ + chunk * 256 + seg * 16;
            *reinterpret_cast<short8*>(&DT[o])     = w0;
            *reinterpret_cast<short8*>(&DT[o + 8]) = w1;
        }
        __syncthreads();
    }
}

// ---------------- prep: combine softmax -> CB bf16 [BS][ES] ----------------
__global__ __launch_bounds__(256) void combine_kernel(const float* __restrict__ L,
                                                      short* __restrict__ CB)
{
    const int t = blockIdx.x;
    const float* row = L + (size_t)t * ES;
    const int tid = threadIdx.x;
    const int wave = tid >> 6, lane = tid & 63;

    f32x4 a = *reinterpret_cast<const f32x4*>(&row[tid * 8]);
    f32x4 b = *reinterpret_cast<const f32x4*>(&row[tid * 8 + 4]);

    float mx = fmaxf(fmaxf(fmaxf(a[0], a[1]), fmaxf(a[2], a[3])),
                     fmaxf(fmaxf(b[0], b[1]), fmaxf(b[2], b[3])));
    #pragma unroll
    for (int off = 32; off > 0; off >>= 1) mx = fmaxf(mx, __shfl_down(mx, off, 64));
    __shared__ float sm[4];
    __shared__ float sbc;
    if (lane == 0) sm[wave] = mx;
    __syncthreads();
    if (tid == 0) sbc = fmaxf(fmaxf(sm[0], sm[1]), fmaxf(sm[2], sm[3]));
    __syncthreads();
    mx = sbc;
    __syncthreads();

    float e[8];
    #pragma unroll
    for (int j = 0; j < 4; ++j) e[j]     = __expf(a[j] - mx);
    #pragma unroll
    for (int j = 0; j < 4; ++j) e[4 + j] = __expf(b[j] - mx);
    float s = 0.f;
    #pragma unroll
    for (int j = 0; j < 8; ++j) s += e[j];
    #pragma unroll
    for (int off = 32; off > 0; off >>= 1) s += __shfl_down(s, off, 64);
    if (lane == 0) sm[wave] = s;
    __syncthreads();
    if (tid == 0) sbc = 1.f / (sm[0] + sm[1] + sm[2] + sm[3]);
    __syncthreads();
    const float rcp = sbc;

    short8 w;
    #pragma unroll
    for (int j = 0; j < 8; ++j) w[j] = f2bf(e[j] * rcp);
    *reinterpret_cast<short8*>(&CB[(size_t)t * ES + tid * 8]) = w;
}

// ---------------- reduce: xt = bf16(sum of 4 fp32 K-split partials) ----------------
__global__ __launch_bounds__(256) void reduce_xt(const float* __restrict__ P,
                                                 short* __restrict__ xt)
{
    const size_t i = ((size_t)blockIdx.x * 256 + threadIdx.x) * 4;
    const size_t CH = (size_t)ES * HID;
    f32x4 s0 = *reinterpret_cast<const f32x4*>(&P[i]);
    f32x4 s1 = *reinterpret_cast<const f32x4*>(&P[i + CH]);
    f32x4 s2 = *reinterpret_cast<const f32x4*>(&P[i + 2 * CH]);
    f32x4 s3 = *reinterpret_cast<const f32x4*>(&P[i + 3 * CH]);
    short4v o;
    #pragma unroll
    for (int j = 0; j < 4; ++j) o[j] = f2bf((s0[j] + s1[j]) + (s2[j] + s3[j]));
    *reinterpret_cast<short4v*>(&xt[i]) = o;
}

// ---------------- bf16 MFMA GEMM: 2-phase reg-prefetch pipeline ----------------
// C[M][N] = A @ B. A bf16 row-major [M][K]. BK=32, 256 threads, 4 waves 2x2.
// BT:  B bf16 [N][K] k-contiguous. Else B float [K][N], BN must be 64.
// EPI: 0 none, 1 silu. NBND: bound N. KBND: bound K on B loads (A must be K-padded).
// CT:  write C transposed (C[n*ldc+m], bf16). NOTE: #K-steps must be EVEN.
template<int BM, int BN, int EPI, bool NBND, bool KBND, bool BT, bool CT,
         typename TB, typename TC>
__global__ __launch_bounds__(256)
void mfma_gemm(const short* __restrict__ A, const TB* __restrict__ B,
               TC* __restrict__ C, int Ndim, int Kdim,
               int lda, int ldb, int ldc,
               long sA, long sB, long sC)
{
    constexpr int BK = 32;
    A += (size_t)blockIdx.z * sA;
    B += (size_t)blockIdx.z * sB;
    C += (size_t)blockIdx.z * sC;
    const int m0 = blockIdx.x * BM;
    const int n0 = blockIdx.y * BN;
    const int tid  = threadIdx.x;
    const int lane = tid & 63;
    const int wid  = tid >> 6;
    const int wm = wid >> 1, wn = wid & 1;
    constexpr int WMT = BM / 2, WNT = BN / 2, MI = WMT / 16, NI = WNT / 16;

    __shared__ short As[BM * 32];
    __shared__ short Bs[BN * 32];

    // staging geometry
    constexpr int AKCH = 32 / (256 / BM);        // shorts per thread (8 or 16)
    constexpr int ANV  = AKCH / 8;               // short8 loads (1 or 2)
    const int amm = tid % BM;
    const int akg = (tid / BM) * AKCH;
    constexpr int BKCH = BT ? (32 / (256 / BN)) : 8;
    constexpr int BNV  = BT ? (BKCH / 8) : 1;
    const int bnn = BT ? (tid % BN) : (tid & 63);
    const int bkg = BT ? ((tid / BN) * BKCH) : ((tid >> 6) * 8);

    f32x4 acc[MI][NI];
    #pragma unroll
    for (int mi = 0; mi < MI; ++mi)
        #pragma unroll
        for (int ni = 0; ni < NI; ++ni)
            acc[mi][ni] = (f32x4){0.f, 0.f, 0.f, 0.f};

    // two named prefetch register sets (no runtime indexing -> stays in VGPRs)
    short8 aRa[2], aRb[2];
    short8 bTa[2], bTb[2];
    f32x4  bFa[2], bFb[2];

#define GLOAD(AR, BTR, BFR, KK) do {                                          \
        _Pragma("unroll")                                                     \
        for (int j = 0; j < ANV; ++j)                                         \
            AR[j] = *reinterpret_cast<const short8*>(                         \
                &A[(size_t)(m0 + amm) * lda + (KK) + akg + 8 * j]);           \
        if constexpr (BT) {                                                   \
            _Pragma("unroll")                                                 \
            for (int j = 0; j < BNV; ++j)                                     \
                BTR[j] = *reinterpret_cast<const short8*>(                    \
                    &B[(size_t)(n0 + bnn) * ldb + (KK) + bkg + 8 * j]);       \
        } else {                                                              \
            const int n_ = n0 + bnn;                                          \
            const bool nok_ = (!NBND) || (n_ < Ndim);                         \
            _Pragma("unroll")                                                 \
            for (int j = 0; j < 8; ++j) {                                     \
                int k_ = (KK) + bkg + j;                                      \
                bool ok_ = nok_ && ((!KBND) || (k_ < Kdim));                  \
                BFR[j >> 2][j & 3] = ok_ ? (float)B[(size_t)k_ * ldb + n_] : 0.f; \
            }                                                                 \
        }                                                                     \
    } while (0)

#define STAGE(AR, BTR, BFR) do {                                              \
        _Pragma("unroll")                                                     \
        for (int j = 0; j < ANV; ++j)                                         \
            *reinterpret_cast<short8*>(&As[swz(amm, akg + 8 * j)]) = AR[j];   \
        if constexpr (BT) {                                                   \
            _Pragma("unroll")                                                 \
            for (int j = 0; j < BNV; ++j)                                     \
                *reinterpret_cast<short8*>(&Bs[swz(bnn, bkg + 8 * j)]) = BTR[j]; \
        } else {                                                              \
            short8 w_;                                                        \
            _Pragma("unroll")                                                 \
            for (int j = 0; j < 8; ++j) w_[j] = f2bf(BFR[j >> 2][j & 3]);     \
            *reinterpret_cast<short8*>(&Bs[swz(bnn, bkg)]) = w_;              \
        }                                                                     \
    } while (0)

#define FRAGMFMA() do {                                                       \
        const int ar_ = lane & 15;                                            \
        const int ac_ = (lane >> 4) * 8;                                      \
        short8 af[MI], bf[NI];                                                \
        _Pragma("unroll")                                                     \
        for (int mi = 0; mi < MI; ++mi)                                       \
            af[mi] = *reinterpret_cast<const short8*>(                        \
                &As[swz(wm * WMT + mi * 16 + ar_, ac_)]);                     \
        _Pragma("unroll")                                                     \
        for (int ni = 0; ni < NI; ++ni)                                       \
            bf[ni] = *reinterpret_cast<const short8*>(                        \
                &Bs[swz(wn * WNT + ni * 16 + ar_, ac_)]);                     \
        _Pragma("unroll")                                                     \
        for (int mi = 0; mi < MI; ++mi)                                       \
            _Pragma("unroll")                                                 \
            for (int ni = 0; ni < NI; ++ni)                                   \
                acc[mi][ni] = __builtin_amdgcn_mfma_f32_16x16x32_bf16(        \
                    af[mi], bf[ni], acc[mi][ni], 0, 0, 0);                    \
    } while (0)

    const int Kloop = KBND ? ((Kdim + 31) & ~31) : Kdim;

    GLOAD(aRa, bTa, bFa, 0);
    for (int k0 = 0; k0 < Kloop; k0 += 2 * BK) {
        // phase 0: stage tile k0, prefetch k0+BK, compute k0
        STAGE(aRa, bTa, bFa);
        __syncthreads();
        GLOAD(aRb, bTb, bFb, k0 + BK);          // K-step count is even: always in range
        FRAGMFMA();
        __syncthreads();
        // phase 1: stage tile k0+BK, prefetch k0+2BK, compute k0+BK
        STAGE(aRb, bTb, bFb);
        __syncthreads();
        if (k0 + 2 * BK < Kloop) GLOAD(aRa, bTa, bFa, k0 + 2 * BK);
        FRAGMFMA();
        __syncthreads();
    }
#undef GLOAD
#undef STAGE
#undef FRAGMFMA

    // ---- epilogue ----
    #pragma unroll
    for (int mi = 0; mi < MI; ++mi) {
        #pragma unroll
        for (int ni = 0; ni < NI; ++ni) {
            const int n = n0 + wn * WNT + ni * 16 + (lane & 15);
            if (NBND && n >= Ndim) continue;
            const int mbase = m0 + wm * WMT + mi * 16 + (lane >> 4) * 4;
            if constexpr (CT) {
                short4v sv;
                #pragma unroll
                for (int r = 0; r < 4; ++r) sv[r] = f2bf(acc[mi][ni][r]);
                *reinterpret_cast<short4v*>(&C[(size_t)n * ldc + mbase]) = sv;
            } else {
                #pragma unroll
                for (int r = 0; r < 4; ++r) {
                    float v = acc[mi][ni][r];
                    if (EPI == 1) v = v / (1.f + __expf(-v));   // silu
                    if constexpr (sizeof(TC) == 2) C[(size_t)(mbase + r) * ldc + n] = f2bf(v);
                    else                           C[(size_t)(mbase + r) * ldc + n] = v;
                }
            }
        }
    }
}

// ---------------- launch ----------------

extern "C" void kernel_launch(void* const* d_in, const int* in_sizes, int n_in,
                              void* d_out, int out_size, void* d_ws, size_t ws_size,
                              hipStream_t stream)
{
    const float* x      = (const float*)d_in[0];
    const float* logits = (const float*)d_in[1];   // [BS][ES]
    const float* w_up   = (const float*)d_in[2];   // [16][1024][2730]
    const float* w_down = (const float*)d_in[3];   // [16][2730][1024]
    float* y = (float*)d_out;

    short* DT    = (short*)((float*)d_ws + 32768);          // [2048][8192] bf16
    short* CB    = DT + (size_t)ES * BS;                    // [8192][2048] bf16
    float* part  = (float*)CB;                              // [4][2048][1024] fp32 (aliases CB; used before combine)
    short* xt    = CB + (size_t)BS * ES;                    // [2048][1024] bf16
    short* h     = xt + (size_t)ES * HID;                   // [16][128][2752] bf16
    short* eoutT = h + (size_t)NEXP * SLOT * FFNP;          // [1024][2048] bf16

    // zero h (pad cols 2730..2751 must be 0 for G3's K-padded A)
    hipMemsetAsync(h, 0, (size_t)NEXP * SLOT * FFNP * sizeof(short), stream);

    dispatch_kernel<<<256, 512, 0, stream>>>(logits, DT);

    // G1: partials[z] = DT[:, z*2048:(z+1)*2048] @ x[z*2048:...]   (K-split x4)
    mfma_gemm<128, 64, 0, false, false, false, false, float, float>
        <<<dim3(16, 16, 4), 256, 0, stream>>>(
            DT, x, part, HID, 2048, BS, HID, HID,
            2048L, 2048L * HID, (long)ES * HID);

    // xt = bf16(sum of 4 partials)
    reduce_xt<<<2048, 256, 0, stream>>>(part, xt);

    // CB (overwrites partials region — partials fully consumed by reduce_xt)
    combine_kernel<<<8192, 256, 0, stream>>>(logits, CB);

    // G2: h[e][128][2752] = silu(xt_e @ w_up_e)   (N bound 2730)
    mfma_gemm<128, 64, 1, true, false, false, false, float, short>
        <<<dim3(1, 43, NEXP), 256, 0, stream>>>(
            xt, w_up, h, FFN, HID, HID, FFN, FFNP,
            (long)SLOT * HID, (long)HID * FFN, (long)SLOT * FFNP);

    // G3: eoutT[n][e*128+m] = (h_e @ w_down_e)^T   (BM=64 -> 512 blocks)
    mfma_gemm<64, 64, 0, false, true, false, true, float, short>
        <<<dim3(2, 16, NEXP), 256, 0, stream>>>(
            h, w_down, eoutT, HID, FFN, FFNP, HID, ES,
            (long)SLOT * FFNP, (long)FFN * HID, (long)SLOT);

    // G4: y[8192][1024] = CB @ eout   (BN=64 -> 1024 blocks; B = eoutT bf16 [N][K])
    mfma_gemm<128, 64, 0, false, false, true, false, short, float>
        <<<dim3(64, 16, 1), 256, 0, stream>>>(
            CB, eoutT, y, HID, ES, ES, ES, HID, 0, 0, 0);
}

// Round 6
// 489.616 us; speedup vs baseline: 4.9066x; 1.0351x over previous
//
#include <hip/hip_runtime.h>
#include <hip/hip_bf16.h>
#include <math.h>

#define BS   8192   // batch*seq tokens
#define SEQQ 2048
#define HID  1024
#define ES   2048   // n_exp * slots
#define FFN  2730
#define FFNP 2752   // FFN padded to multiple of 32
#define NEXP 16
#define SLOT 128

typedef __attribute__((ext_vector_type(4))) float  f32x4;
typedef __attribute__((ext_vector_type(8))) short  short8;
typedef __attribute__((ext_vector_type(4))) short  short4v;

__device__ __forceinline__ short f2bf(float f) {
    union { float f; unsigned u; } v; v.f = f;
    unsigned r = v.u + 0x7fffu + ((v.u >> 16) & 1u);   // RNE
    return (short)(r >> 16);
}

// Swizzled LDS index (shorts). Row = 32 shorts = 64B, slot' = slot ^ ((row>>1)&3).
// Verified conflict-free round 4/5: SQ_LDS_BANK_CONFLICT == 0.
__device__ __forceinline__ int swz(int row, int kk) {
    return (row << 5) + ((((kk >> 3) ^ (row >> 1)) & 3) << 3) + (kk & 7);
}

// ---------------- prep: dispatch softmax -> DT bf16 [ES][BS] ----------------
__global__ __launch_bounds__(512) void dispatch_kernel(const float* __restrict__ L,
                                                       short* __restrict__ DT)
{
    const int b  = blockIdx.x >> 6;
    const int c0 = (blockIdx.x & 63) * 32;
    const int tc = threadIdx.x & 31;    // column within tile
    const int rg = threadIdx.x >> 5;    // 0..15 row group
    const int c  = c0 + tc;
    const float* base = L + (size_t)b * SEQQ * ES + c;

    __shared__ float red[16][33];

    float mx = -1e30f;
    for (int r = rg; r < SEQQ; r += 16)
        mx = fmaxf(mx, base[(size_t)r * ES]);
    red[rg][tc] = mx;
    __syncthreads();
    if (rg == 0) {
        #pragma unroll
        for (int i = 1; i < 16; ++i) mx = fmaxf(mx, red[i][tc]);
        red[0][tc] = mx;
    }
    __syncthreads();
    mx = red[0][tc];
    __syncthreads();

    float s = 0.f;
    for (int r = rg; r < SEQQ; r += 16)
        s += __expf(base[(size_t)r * ES] - mx);
    red[rg][tc] = s;
    __syncthreads();
    if (rg == 0) {
        #pragma unroll
        for (int i = 1; i < 16; ++i) s += red[i][tc];
        red[0][tc] = 1.f / s;
    }
    __syncthreads();
    const float rcp = red[0][tc];
    __syncthreads();

    __shared__ short T[32][264];
    for (int chunk = 0; chunk < SEQQ / 256; ++chunk) {
        #pragma unroll
        for (int j = 0; j < 16; ++j) {
            int r = chunk * 256 + rg * 16 + j;
            float v = base[(size_t)r * ES];
            T[tc][rg * 16 + j] = f2bf(__expf(v - mx) * rcp);
        }
        __syncthreads();
        {
            const int row = threadIdx.x >> 4;
            const int seg = threadIdx.x & 15;
            short8 w0 = *reinterpret_cast<const short8*>(&T[row][seg * 16]);
            short8 w1 = *reinterpret_cast<const short8*>(&T[row][seg * 16 + 8]);
            size_t o = (size_t)(c0 + row) * BS + (size_t)b * SEQQ + chunk * 256 + seg * 16;
            *reinterpret_cast<short8*>(&DT[o])     = w0;
            *reinterpret_cast<short8*>(&DT[o + 8]) = w1;
        }
        __syncthreads();
    }
}

// ---------------- prep: combine softmax -> CB bf16 [BS][ES] ----------------
__global__ __launch_bounds__(256) void combine_kernel(const float* __restrict__ L,
                                                      short* __restrict__ CB)
{
    const int t = blockIdx.x;
    const float* row = L + (size_t)t * ES;
    const int tid = threadIdx.x;
    const int wave = tid >> 6, lane = tid & 63;

    f32x4 a = *reinterpret_cast<const f32x4*>(&row[tid * 8]);
    f32x4 b = *reinterpret_cast<const f32x4*>(&row[tid * 8 + 4]);

    float mx = fmaxf(fmaxf(fmaxf(a[0], a[1]), fmaxf(a[2], a[3])),
                     fmaxf(fmaxf(b[0], b[1]), fmaxf(b[2], b[3])));
    #pragma unroll
    for (int off = 32; off > 0; off >>= 1) mx = fmaxf(mx, __shfl_down(mx, off, 64));
    __shared__ float sm[4];
    __shared__ float sbc;
    if (lane == 0) sm[wave] = mx;
    __syncthreads();
    if (tid == 0) sbc = fmaxf(fmaxf(sm[0], sm[1]), fmaxf(sm[2], sm[3]));
    __syncthreads();
    mx = sbc;
    __syncthreads();

    float e[8];
    #pragma unroll
    for (int j = 0; j < 4; ++j) e[j]     = __expf(a[j] - mx);
    #pragma unroll
    for (int j = 0; j < 4; ++j) e[4 + j] = __expf(b[j] - mx);
    float s = 0.f;
    #pragma unroll
    for (int j = 0; j < 8; ++j) s += e[j];
    #pragma unroll
    for (int off = 32; off > 0; off >>= 1) s += __shfl_down(s, off, 64);
    if (lane == 0) sm[wave] = s;
    __syncthreads();
    if (tid == 0) sbc = 1.f / (sm[0] + sm[1] + sm[2] + sm[3]);
    __syncthreads();
    const float rcp = sbc;

    short8 w;
    #pragma unroll
    for (int j = 0; j < 8; ++j) w[j] = f2bf(e[j] * rcp);
    *reinterpret_cast<short8*>(&CB[(size_t)t * ES + tid * 8]) = w;
}

// ---------------- reduce: xt = bf16(sum of 4 fp32 K-split partials) ----------------
__global__ __launch_bounds__(256) void reduce_xt(const float* __restrict__ P,
                                                 short* __restrict__ xt)
{
    const size_t i = ((size_t)blockIdx.x * 256 + threadIdx.x) * 4;
    const size_t CH = (size_t)ES * HID;
    f32x4 s0 = *reinterpret_cast<const f32x4*>(&P[i]);
    f32x4 s1 = *reinterpret_cast<const f32x4*>(&P[i + CH]);
    f32x4 s2 = *reinterpret_cast<const f32x4*>(&P[i + 2 * CH]);
    f32x4 s3 = *reinterpret_cast<const f32x4*>(&P[i + 3 * CH]);
    short4v o;
    #pragma unroll
    for (int j = 0; j < 4; ++j) o[j] = f2bf((s0[j] + s1[j]) + (s2[j] + s3[j]));
    *reinterpret_cast<short4v*>(&xt[i]) = o;
}

// ---------------- bf16 MFMA GEMM: dbuf LDS + depth-2 reg prefetch ----------------
// C[M][N] = A @ B. A bf16 row-major [M][K]. BK=32, 256 threads, 4 waves 2x2.
// BT:  B bf16 [N][K] k-contiguous. Else B float [K][N], BN must be 64.
// EPI: 0 none, 1 silu. NBND: bound N. KBND: bound K on B loads (A must be K-padded).
// CT:  write C transposed. #K-steps must be EVEN and >= 2.
// Schedule per phase: {GLOAD(t+2) | COMPUTE(cur) | STAGE(other <- regs t+1)} sync
//  -> one barrier per K-step; each global load has ~2 compute phases of latency cover.
template<int BM, int BN, int EPI, bool NBND, bool KBND, bool BT, bool CT,
         typename TB, typename TC>
__global__ __launch_bounds__(256)
void mfma_gemm(const short* __restrict__ A, const TB* __restrict__ B,
               TC* __restrict__ C, int Ndim, int Kdim,
               int lda, int ldb, int ldc,
               long sA, long sB, long sC)
{
    constexpr int BK = 32;
    A += (size_t)blockIdx.z * sA;
    B += (size_t)blockIdx.z * sB;
    C += (size_t)blockIdx.z * sC;
    const int m0 = blockIdx.x * BM;
    const int n0 = blockIdx.y * BN;
    const int tid  = threadIdx.x;
    const int lane = tid & 63;
    const int wid  = tid >> 6;
    const int wm = wid >> 1, wn = wid & 1;
    constexpr int WMT = BM / 2, WNT = BN / 2, MI = WMT / 16, NI = WNT / 16;

    __shared__ short As0[BM * 32], As1[BM * 32];
    __shared__ short Bs0[BN * 32], Bs1[BN * 32];

    // staging geometry
    constexpr int AKCH = 32 / (256 / BM);        // shorts per thread (8 or 16)
    constexpr int ANV  = AKCH / 8;               // short8 loads (1 or 2)
    const int amm = tid % BM;
    const int akg = (tid / BM) * AKCH;
    constexpr int BKCH = BT ? (32 / (256 / BN)) : 8;
    constexpr int BNV  = BT ? (BKCH / 8) : 1;
    const int bnn = BT ? (tid % BN) : (tid & 63);
    const int bkg = BT ? ((tid / BN) * BKCH) : ((tid >> 6) * 8);

    f32x4 acc[MI][NI];
    #pragma unroll
    for (int mi = 0; mi < MI; ++mi)
        #pragma unroll
        for (int ni = 0; ni < NI; ++ni)
            acc[mi][ni] = (f32x4){0.f, 0.f, 0.f, 0.f};

    // two named prefetch register sets (compile-time indexing only)
    short8 aRa[ANV], aRb[ANV];
    short8 bTa[BNV], bTb[BNV];
    f32x4  bFa[2],   bFb[2];

#define GLOAD(AR, BTR, BFR, KK) do {                                          \
        _Pragma("unroll")                                                     \
        for (int j = 0; j < ANV; ++j)                                         \
            AR[j] = *reinterpret_cast<const short8*>(                         \
                &A[(size_t)(m0 + amm) * lda + (KK) + akg + 8 * j]);           \
        if constexpr (BT) {                                                   \
            _Pragma("unroll")                                                 \
            for (int j = 0; j < BNV; ++j)                                     \
                BTR[j] = *reinterpret_cast<const short8*>(                    \
                    &B[(size_t)(n0 + bnn) * ldb + (KK) + bkg + 8 * j]);       \
        } else {                                                              \
            const int n_ = n0 + bnn;                                          \
            const bool nok_ = (!NBND) || (n_ < Ndim);                         \
            _Pragma("unroll")                                                 \
            for (int j = 0; j < 8; ++j) {                                     \
                int k_ = (KK) + bkg + j;                                      \
                bool ok_ = nok_ && ((!KBND) || (k_ < Kdim));                  \
                BFR[j >> 2][j & 3] = ok_ ? (float)B[(size_t)k_ * ldb + n_] : 0.f; \
            }                                                                 \
        }                                                                     \
    } while (0)

#define STAGE(ASP, BSP, AR, BTR, BFR) do {                                    \
        _Pragma("unroll")                                                     \
        for (int j = 0; j < ANV; ++j)                                         \
            *reinterpret_cast<short8*>(&(ASP)[swz(amm, akg + 8 * j)]) = AR[j];\
        if constexpr (BT) {                                                   \
            _Pragma("unroll")                                                 \
            for (int j = 0; j < BNV; ++j)                                     \
                *reinterpret_cast<short8*>(&(BSP)[swz(bnn, bkg + 8 * j)]) = BTR[j]; \
        } else {                                                              \
            short8 w_;                                                        \
            _Pragma("unroll")                                                 \
            for (int j = 0; j < 8; ++j) w_[j] = f2bf(BFR[j >> 2][j & 3]);     \
            *reinterpret_cast<short8*>(&(BSP)[swz(bnn, bkg)]) = w_;           \
        }                                                                     \
    } while (0)

#define COMPUTE(ASP, BSP) do {                                                \
        const int ar_ = lane & 15;                                            \
        const int ac_ = (lane >> 4) * 8;                                      \
        short8 af[MI], bf[NI];                                                \
        _Pragma("unroll")                                                     \
        for (int mi = 0; mi < MI; ++mi)                                       \
            af[mi] = *reinterpret_cast<const short8*>(                        \
                &(ASP)[swz(wm * WMT + mi * 16 + ar_, ac_)]);                  \
        _Pragma("unroll")                                                     \
        for (int ni = 0; ni < NI; ++ni)                                       \
            bf[ni] = *reinterpret_cast<const short8*>(                        \
                &(BSP)[swz(wn * WNT + ni * 16 + ar_, ac_)]);                  \
        _Pragma("unroll")                                                     \
        for (int mi = 0; mi < MI; ++mi)                                       \
            _Pragma("unroll")                                                 \
            for (int ni = 0; ni < NI; ++ni)                                   \
                acc[mi][ni] = __builtin_amdgcn_mfma_f32_16x16x32_bf16(        \
                    af[mi], bf[ni], acc[mi][ni], 0, 0, 0);                    \
    } while (0)

    const int Kloop = KBND ? ((Kdim + 31) & ~31) : Kdim;
    const int nt = Kloop / BK;   // even, >= 2

    GLOAD(aRa, bTa, bFa, 0);
    GLOAD(aRb, bTb, bFb, BK);
    STAGE(As0, Bs0, aRa, bTa, bFa);
    __syncthreads();

    for (int t = 0; t < nt; t += 2) {
        const bool p2 = (t + 2 < nt);
        const bool p3 = (t + 3 < nt);
        if (p2) GLOAD(aRa, bTa, bFa, (t + 2) * BK);
        COMPUTE(As0, Bs0);                      // tile t
        STAGE(As1, Bs1, aRb, bTb, bFb);         // tile t+1 (waits its vmcnt here)
        __syncthreads();
        if (p3) GLOAD(aRb, bTb, bFb, (t + 3) * BK);
        COMPUTE(As1, Bs1);                      // tile t+1
        if (p2) STAGE(As0, Bs0, aRa, bTa, bFa); // tile t+2
        __syncthreads();
    }
#undef GLOAD
#undef STAGE
#undef COMPUTE

    // ---- epilogue ----
    #pragma unroll
    for (int mi = 0; mi < MI; ++mi) {
        #pragma unroll
        for (int ni = 0; ni < NI; ++ni) {
            const int n = n0 + wn * WNT + ni * 16 + (lane & 15);
            if (NBND && n >= Ndim) continue;
            const int mbase = m0 + wm * WMT + mi * 16 + (lane >> 4) * 4;
            if constexpr (CT) {
                short4v sv;
                #pragma unroll
                for (int r = 0; r < 4; ++r) sv[r] = f2bf(acc[mi][ni][r]);
                *reinterpret_cast<short4v*>(&C[(size_t)n * ldc + mbase]) = sv;
            } else {
                #pragma unroll
                for (int r = 0; r < 4; ++r) {
                    float v = acc[mi][ni][r];
                    if (EPI == 1) v = v / (1.f + __expf(-v));   // silu
                    if constexpr (sizeof(TC) == 2) C[(size_t)(mbase + r) * ldc + n] = f2bf(v);
                    else                           C[(size_t)(mbase + r) * ldc + n] = v;
                }
            }
        }
    }
}

// ---------------- launch ----------------

extern "C" void kernel_launch(void* const* d_in, const int* in_sizes, int n_in,
                              void* d_out, int out_size, void* d_ws, size_t ws_size,
                              hipStream_t stream)
{
    const float* x      = (const float*)d_in[0];
    const float* logits = (const float*)d_in[1];   // [BS][ES]
    const float* w_up   = (const float*)d_in[2];   // [16][1024][2730]
    const float* w_down = (const float*)d_in[3];   // [16][2730][1024]
    float* y = (float*)d_out;

    short* DT    = (short*)((float*)d_ws + 32768);          // [2048][8192] bf16
    short* CB    = DT + (size_t)ES * BS;                    // [8192][2048] bf16
    float* part  = (float*)CB;                              // [4][2048][1024] fp32 (aliases CB)
    short* xt    = CB + (size_t)BS * ES;                    // [2048][1024] bf16
    short* h     = xt + (size_t)ES * HID;                   // [16][128][2752] bf16
    short* eoutT = h + (size_t)NEXP * SLOT * FFNP;          // [1024][2048] bf16

    // zero h (pad cols 2730..2751 must be 0 for G3's K-padded A)
    hipMemsetAsync(h, 0, (size_t)NEXP * SLOT * FFNP * sizeof(short), stream);

    dispatch_kernel<<<256, 512, 0, stream>>>(logits, DT);

    // G1: partials[z] = DT[:, z*2048:(z+1)*2048] @ x[z*2048:...]   (K-split x4, nt=64)
    mfma_gemm<128, 64, 0, false, false, false, false, float, float>
        <<<dim3(16, 16, 4), 256, 0, stream>>>(
            DT, x, part, HID, 2048, BS, HID, HID,
            2048L, 2048L * HID, (long)ES * HID);

    // xt = bf16(sum of 4 partials)
    reduce_xt<<<2048, 256, 0, stream>>>(part, xt);

    // CB (overwrites partials region — fully consumed by reduce_xt)
    combine_kernel<<<8192, 256, 0, stream>>>(logits, CB);

    // G2: h[e][128][2752] = silu(xt_e @ w_up_e)   (N bound 2730, nt=32)
    mfma_gemm<128, 64, 1, true, false, false, false, float, short>
        <<<dim3(1, 43, NEXP), 256, 0, stream>>>(
            xt, w_up, h, FFN, HID, HID, FFN, FFNP,
            (long)SLOT * HID, (long)HID * FFN, (long)SLOT * FFNP);

    // G3: eoutT[n][e*128+m] = (h_e @ w_down_e)^T   (nt=86, K bound 2730 on B)
    mfma_gemm<64, 64, 0, false, true, false, true, float, short>
        <<<dim3(2, 16, NEXP), 256, 0, stream>>>(
            h, w_down, eoutT, HID, FFN, FFNP, HID, ES,
            (long)SLOT * FFNP, (long)FFN * HID, (long)SLOT);

    // G4: y[8192][1024] = CB @ eout   (BT, nt=64)
    mfma_gemm<128, 64, 0, false, false, true, false, short, float>
        <<<dim3(64, 16, 1), 256, 0, stream>>>(
            CB, eoutT, y, HID, ES, ES, ES, HID, 0, 0, 0);
}

// Round 7
// 397.592 us; speedup vs baseline: 6.0422x; 1.2315x over previous
//
#include <hip/hip_runtime.h>
#include <hip/hip_bf16.h>
#include <math.h>

#define BS   8192   // batch*seq tokens
#define SEQQ 2048
#define HID  1024
#define ES   2048   // n_exp * slots
#define FFN  2730
#define FFNP 2752   // FFN padded to multiple of 32
#define NEXP 16
#define SLOT 128

typedef __attribute__((ext_vector_type(4))) float  f32x4;
typedef __attribute__((ext_vector_type(8))) short  short8;
typedef __attribute__((ext_vector_type(4))) short  short4v;

__device__ __forceinline__ short f2bf(float f) {
    union { float f; unsigned u; } v; v.f = f;
    unsigned r = v.u + 0x7fffu + ((v.u >> 16) & 1u);   // RNE
    return (short)(r >> 16);
}

// Swizzled LDS index (shorts). Row = 32 shorts = 64B = 4 slots of 16B.
// slot' = slot ^ ((row>>1)&3). Verified conflict-free (rounds 4-6: 0 conflicts).
__device__ __forceinline__ int swz(int row, int kk) {
    return (row << 5) + ((((kk >> 3) ^ (row >> 1)) & 3) << 3) + (kk & 7);
}

// global -> LDS direct 16B (width=16). LDS dest must be wave-uniform;
// HW adds lane*16. Source is per-lane (pre-swizzled so linear LDS ==
// swizzled layout; same XOR involution as swz()).
#define GLD16(gp, lp)                                                   \
    __builtin_amdgcn_global_load_lds(                                   \
        (__attribute__((address_space(1))) void*)(gp),                  \
        (__attribute__((address_space(3))) void*)(lp), 16, 0, 0)

// ---------------- prep: dispatch softmax -> DT bf16 [ES][BS] ----------------
__global__ __launch_bounds__(512) void dispatch_kernel(const float* __restrict__ L,
                                                       short* __restrict__ DT)
{
    const int b  = blockIdx.x >> 6;
    const int c0 = (blockIdx.x & 63) * 32;
    const int tc = threadIdx.x & 31;    // column within tile
    const int rg = threadIdx.x >> 5;    // 0..15 row group
    const int c  = c0 + tc;
    const float* base = L + (size_t)b * SEQQ * ES + c;

    __shared__ float red[16][33];

    float mx = -1e30f;
    for (int r = rg; r < SEQQ; r += 16)
        mx = fmaxf(mx, base[(size_t)r * ES]);
    red[rg][tc] = mx;
    __syncthreads();
    if (rg == 0) {
        #pragma unroll
        for (int i = 1; i < 16; ++i) mx = fmaxf(mx, red[i][tc]);
        red[0][tc] = mx;
    }
    __syncthreads();
    mx = red[0][tc];
    __syncthreads();

    float s = 0.f;
    for (int r = rg; r < SEQQ; r += 16)
        s += __expf(base[(size_t)r * ES] - mx);
    red[rg][tc] = s;
    __syncthreads();
    if (rg == 0) {
        #pragma unroll
        for (int i = 1; i < 16; ++i) s += red[i][tc];
        red[0][tc] = 1.f / s;
    }
    __syncthreads();
    const float rcp = red[0][tc];
    __syncthreads();

    __shared__ short T[32][264];
    for (int chunk = 0; chunk < SEQQ / 256; ++chunk) {
        #pragma unroll
        for (int j = 0; j < 16; ++j) {
            int r = chunk * 256 + rg * 16 + j;
            float v = base[(size_t)r * ES];
            T[tc][rg * 16 + j] = f2bf(__expf(v - mx) * rcp);
        }
        __syncthreads();
        {
            const int row = threadIdx.x >> 4;
            const int seg = threadIdx.x & 15;
            short8 w0 = *reinterpret_cast<const short8*>(&T[row][seg * 16]);
            short8 w1 = *reinterpret_cast<const short8*>(&T[row][seg * 16 + 8]);
            size_t o = (size_t)(c0 + row) * BS + (size_t)b * SEQQ + chunk * 256 + seg * 16;
            *reinterpret_cast<short8*>(&DT[o])     = w0;
            *reinterpret_cast<short8*>(&DT[o + 8]) = w1;
        }
        __syncthreads();
    }
}

// ---------------- prep: combine softmax -> CB bf16 [BS][ES] ----------------
__global__ __launch_bounds__(256) void combine_kernel(const float* __restrict__ L,
                                                      short* __restrict__ CB)
{
    const int t = blockIdx.x;
    const float* row = L + (size_t)t * ES;
    const int tid = threadIdx.x;
    const int wave = tid >> 6, lane = tid & 63;

    f32x4 a = *reinterpret_cast<const f32x4*>(&row[tid * 8]);
    f32x4 b = *reinterpret_cast<const f32x4*>(&row[tid * 8 + 4]);

    float mx = fmaxf(fmaxf(fmaxf(a[0], a[1]), fmaxf(a[2], a[3])),
                     fmaxf(fmaxf(b[0], b[1]), fmaxf(b[2], b[3])));
    #pragma unroll
    for (int off = 32; off > 0; off >>= 1) mx = fmaxf(mx, __shfl_down(mx, off, 64));
    __shared__ float sm[4];
    __shared__ float sbc;
    if (lane == 0) sm[wave] = mx;
    __syncthreads();
    if (tid == 0) sbc = fmaxf(fmaxf(sm[0], sm[1]), fmaxf(sm[2], sm[3]));
    __syncthreads();
    mx = sbc;
    __syncthreads();

    float e[8];
    #pragma unroll
    for (int j = 0; j < 4; ++j) e[j]     = __expf(a[j] - mx);
    #pragma unroll
    for (int j = 0; j < 4; ++j) e[4 + j] = __expf(b[j] - mx);
    float s = 0.f;
    #pragma unroll
    for (int j = 0; j < 8; ++j) s += e[j];
    #pragma unroll
    for (int off = 32; off > 0; off >>= 1) s += __shfl_down(s, off, 64);
    if (lane == 0) sm[wave] = s;
    __syncthreads();
    if (tid == 0) sbc = 1.f / (sm[0] + sm[1] + sm[2] + sm[3]);
    __syncthreads();
    const float rcp = sbc;

    short8 w;
    #pragma unroll
    for (int j = 0; j < 8; ++j) w[j] = f2bf(e[j] * rcp);
    *reinterpret_cast<short8*>(&CB[(size_t)t * ES + tid * 8]) = w;
}

// ---------------- prep: x fp32 [8192][1024] -> xT bf16 [1024][8192] ----------------
__global__ __launch_bounds__(256) void transpose_x(const float* __restrict__ X,
                                                   short* __restrict__ XT)
{
    __shared__ short T[64][72];   // 144B rows: 16B-aligned, 2-way-free bank stride
    const int tid = threadIdx.x;
    const int k0 = blockIdx.x * 64;   // 128
    const int n0 = blockIdx.y * 64;   // 16
    {
        const int kk = tid >> 2;
        const int nn = (tid & 3) * 16;
        const float* src = X + (size_t)(k0 + kk) * HID + n0 + nn;
        #pragma unroll
        for (int j = 0; j < 4; ++j) {
            f32x4 v = *reinterpret_cast<const f32x4*>(src + 4 * j);
            short4v s;
            #pragma unroll
            for (int i = 0; i < 4; ++i) s[i] = f2bf(v[i]);
            *reinterpret_cast<short4v*>(&T[kk][nn + 4 * j]) = s;
        }
    }
    __syncthreads();
    {
        const int nn  = tid >> 2;
        const int kk4 = (tid & 3) * 16;
        short8 w0, w1;
        #pragma unroll
        for (int i = 0; i < 8; ++i) w0[i] = T[kk4 + i][nn];
        #pragma unroll
        for (int i = 0; i < 8; ++i) w1[i] = T[kk4 + 8 + i][nn];
        size_t o = (size_t)(n0 + nn) * BS + k0 + kk4;
        *reinterpret_cast<short8*>(&XT[o])     = w0;
        *reinterpret_cast<short8*>(&XT[o + 8]) = w1;
    }
}

// ---------------- reduce: xt = bf16(sum of 4 fp32 K-split partials) ----------------
__global__ __launch_bounds__(256) void reduce_xt(const float* __restrict__ P,
                                                 short* __restrict__ xt)
{
    const size_t i = ((size_t)blockIdx.x * 256 + threadIdx.x) * 4;
    const size_t CH = (size_t)ES * HID;
    f32x4 s0 = *reinterpret_cast<const f32x4*>(&P[i]);
    f32x4 s1 = *reinterpret_cast<const f32x4*>(&P[i + CH]);
    f32x4 s2 = *reinterpret_cast<const f32x4*>(&P[i + 2 * CH]);
    f32x4 s3 = *reinterpret_cast<const f32x4*>(&P[i + 3 * CH]);
    short4v o;
    #pragma unroll
    for (int j = 0; j < 4; ++j) o[j] = f2bf((s0[j] + s1[j]) + (s2[j] + s3[j]));
    *reinterpret_cast<short4v*>(&xt[i]) = o;
}

// ---------------- bf16 MFMA GEMM: global_load_lds + dbuf, 1 barrier/step ----------
// C[M][N] = A @ B. A bf16 row-major [M][K]. BK=32, 256 threads, 4 waves 2x2.
// BT:  B bf16 [N][K] k-contiguous -> global_load_lds. Else B float [K][N], BN==64,
//      reg-staged (scalar loads) + f2bf pack + swizzled ds_write_b128.
// EPI: 0 none, 1 silu. NBND: bound N (B loads + C stores).
// KBND: bound K on float-B loads (A must be K-padded). CT: C transposed bf16.
// #K-steps must be EVEN (>=2).
template<int BM, int BN, int EPI, bool NBND, bool KBND, bool BT, bool CT,
         typename TB, typename TC>
__global__ __launch_bounds__(256)
void mfma_gemm(const short* __restrict__ A, const TB* __restrict__ B,
               TC* __restrict__ C, int Ndim, int Kdim,
               int lda, int ldb, int ldc,
               long sA, long sB, long sC)
{
    constexpr int BK = 32;
    A += (size_t)blockIdx.z * sA;
    B += (size_t)blockIdx.z * sB;
    C += (size_t)blockIdx.z * sC;
    const int m0 = blockIdx.x * BM;
    const int n0 = blockIdx.y * BN;
    const int tid  = threadIdx.x;
    const int lane = tid & 63;
    const int wid  = tid >> 6;
    const int wm = wid >> 1, wn = wid & 1;
    constexpr int WMT = BM / 2, WNT = BN / 2, MI = WMT / 16, NI = WNT / 16;
    constexpr int PA = BM / 64;                  // gload_lds passes for A
    constexpr int PB = BN / 64;                  // gload_lds passes for B (BT)

    __shared__ __align__(16) short As0[BM * 32], As1[BM * 32];
    __shared__ __align__(16) short Bs0[BN * 32], Bs1[BN * 32];

    f32x4 acc[MI][NI];
    #pragma unroll
    for (int mi = 0; mi < MI; ++mi)
        #pragma unroll
        for (int ni = 0; ni < NI; ++ni)
            acc[mi][ni] = (f32x4){0.f, 0.f, 0.f, 0.f};

    // float-B staging geometry (BN == 64)
    const int bnn = tid & 63;
    const int bks = (tid >> 6) * 8;

    // issue tile loads: gload_lds for A (and B if BT); float-B -> regs
    auto ISSUE = [&](short* ASP, short* BSP, int kk, f32x4* bF) {
        #pragma unroll
        for (int p = 0; p < PA; ++p) {
            const int slot = p * 256 + tid;
            const int row  = slot >> 2;
            const int seg  = (slot & 3) ^ ((row >> 1) & 3);   // pre-swizzled source
            GLD16(&A[(size_t)(m0 + row) * lda + kk + seg * 8],
                  &ASP[(p * 256 + wid * 64) * 8]);
        }
        if constexpr (BT) {
            #pragma unroll
            for (int p = 0; p < PB; ++p) {
                const int slot = p * 256 + tid;
                const int row  = slot >> 2;
                const int seg  = (slot & 3) ^ ((row >> 1) & 3);
                GLD16(&B[(size_t)(n0 + row) * ldb + kk + seg * 8],
                      &BSP[(p * 256 + wid * 64) * 8]);
            }
        } else {
            const int n_ = n0 + bnn;
            const bool nok_ = (!NBND) || (n_ < Ndim);
            #pragma unroll
            for (int j = 0; j < 8; ++j) {
                int k_ = kk + bks + j;
                bool ok_ = nok_ && ((!KBND) || (k_ < Kdim));
                bF[j >> 2][j & 3] = ok_ ? (float)B[(size_t)k_ * ldb + n_] : 0.f;
            }
        }
    };

    auto PACKB = [&](short* BSP, const f32x4* bF) {
        short8 w;
        #pragma unroll
        for (int j = 0; j < 8; ++j) w[j] = f2bf(bF[j >> 2][j & 3]);
        *reinterpret_cast<short8*>(&BSP[swz(bnn, bks)]) = w;
    };

    auto COMPUTE = [&](const short* ASP, const short* BSP) {
        const int ar = lane & 15;
        const int ac = (lane >> 4) * 8;
        short8 af[MI], bf[NI];
        #pragma unroll
        for (int mi = 0; mi < MI; ++mi)
            af[mi] = *reinterpret_cast<const short8*>(&ASP[swz(wm * WMT + mi * 16 + ar, ac)]);
        #pragma unroll
        for (int ni = 0; ni < NI; ++ni)
            bf[ni] = *reinterpret_cast<const short8*>(&BSP[swz(wn * WNT + ni * 16 + ar, ac)]);
        #pragma unroll
        for (int mi = 0; mi < MI; ++mi)
            #pragma unroll
            for (int ni = 0; ni < NI; ++ni)
                acc[mi][ni] = __builtin_amdgcn_mfma_f32_16x16x32_bf16(
                    af[mi], bf[ni], acc[mi][ni], 0, 0, 0);
    };

    const int Kloop = KBND ? ((Kdim + 31) & ~31) : Kdim;
    const int nt = Kloop / BK;   // even, >= 2

    f32x4 bF0[2], bF1[2];
    ISSUE(As0, Bs0, 0, bF0);
    if constexpr (!BT) PACKB(Bs0, bF0);
    __syncthreads();                              // drains gload_lds for tile 0

    for (int t = 0; t < nt; t += 2) {
        ISSUE(As1, Bs1, (t + 1) * BK, bF1);       // t+1 always < nt (nt even)
        COMPUTE(As0, Bs0);
        if constexpr (!BT) PACKB(Bs1, bF1);
        __syncthreads();

        const bool p2 = (t + 2 < nt);
        if (p2) ISSUE(As0, Bs0, (t + 2) * BK, bF0);
        COMPUTE(As1, Bs1);
        if (p2) { if constexpr (!BT) PACKB(Bs0, bF0); }
        __syncthreads();
    }

    // ---- epilogue ----
    #pragma unroll
    for (int mi = 0; mi < MI; ++mi) {
        #pragma unroll
        for (int ni = 0; ni < NI; ++ni) {
            const int n = n0 + wn * WNT + ni * 16 + (lane & 15);
            if (NBND && n >= Ndim) continue;
            const int mbase = m0 + wm * WMT + mi * 16 + (lane >> 4) * 4;
            if constexpr (CT) {
                short4v sv;
                #pragma unroll
                for (int r = 0; r < 4; ++r) sv[r] = f2bf(acc[mi][ni][r]);
                *reinterpret_cast<short4v*>(&C[(size_t)n * ldc + mbase]) = sv;
            } else {
                #pragma unroll
                for (int r = 0; r < 4; ++r) {
                    float v = acc[mi][ni][r];
                    if (EPI == 1) v = v / (1.f + __expf(-v));   // silu
                    if constexpr (sizeof(TC) == 2) C[(size_t)(mbase + r) * ldc + n] = f2bf(v);
                    else                           C[(size_t)(mbase + r) * ldc + n] = v;
                }
            }
        }
    }
}

// ---------------- launch ----------------

extern "C" void kernel_launch(void* const* d_in, const int* in_sizes, int n_in,
                              void* d_out, int out_size, void* d_ws, size_t ws_size,
                              hipStream_t stream)
{
    const float* x      = (const float*)d_in[0];
    const float* logits = (const float*)d_in[1];   // [BS][ES]
    const float* w_up   = (const float*)d_in[2];   // [16][1024][2730]
    const float* w_down = (const float*)d_in[3];   // [16][2730][1024]
    float* y = (float*)d_out;

    float* wsf   = (float*)d_ws;
    short* DT    = (short*)(wsf + 32768);                  // [2048][8192] bf16
    short* CB    = DT + (size_t)ES * BS;                   // [8192][2048] bf16
    float* part  = (float*)CB;                             // [4][2048][1024] fp32 (aliases CB)
    short* xt    = CB + (size_t)BS * ES;                   // [2048][1024] bf16
    short* h     = xt + (size_t)ES * HID;                  // [16][128][2752] bf16
    short* eoutT = h + (size_t)NEXP * SLOT * FFNP;         // [1024][2048] bf16
    short* xT    = eoutT + (size_t)HID * ES;               // [1024][8192] bf16
    const size_t need = (size_t)((char*)(xT + (size_t)HID * BS) - (char*)d_ws);
    const bool use_bt = ws_size >= need;

    // zero h (pad cols 2730..2751 must be 0 for G3's K-padded A)
    hipMemsetAsync(h, 0, (size_t)NEXP * SLOT * FFNP * sizeof(short), stream);

    dispatch_kernel<<<256, 512, 0, stream>>>(logits, DT);

    // G1: partials[z] = DT[:, z*2048:...] @ x[z*2048:...]   (K-split x4, nt=64)
    if (use_bt) {
        transpose_x<<<dim3(128, 16, 1), 256, 0, stream>>>(x, xT);
        mfma_gemm<128, 128, 0, false, false, true, false, short, float>
            <<<dim3(16, 8, 4), 256, 0, stream>>>(
                DT, xT, part, HID, 2048, BS, BS, HID,
                2048L, 2048L, (long)ES * HID);
    } else {
        mfma_gemm<128, 64, 0, false, false, false, false, float, float>
            <<<dim3(16, 16, 4), 256, 0, stream>>>(
                DT, x, part, HID, 2048, BS, HID, HID,
                2048L, 2048L * HID, (long)ES * HID);
    }

    // xt = bf16(sum of 4 partials)
    reduce_xt<<<2048, 256, 0, stream>>>(part, xt);

    // CB (overwrites partials region — fully consumed by reduce_xt)
    combine_kernel<<<8192, 256, 0, stream>>>(logits, CB);

    // G2: h[e][128][2752] = silu(xt_e @ w_up_e)   (N bound 2730, nt=32)
    mfma_gemm<128, 64, 1, true, false, false, false, float, short>
        <<<dim3(1, 43, NEXP), 256, 0, stream>>>(
            xt, w_up, h, FFN, HID, HID, FFN, FFNP,
            (long)SLOT * HID, (long)HID * FFN, (long)SLOT * FFNP);

    // G3: eoutT[n][e*128+m] = (h_e @ w_down_e)^T   (nt=86, K bound 2730 on B)
    mfma_gemm<64, 64, 0, false, true, false, true, float, short>
        <<<dim3(2, 16, NEXP), 256, 0, stream>>>(
            h, w_down, eoutT, HID, FFN, FFNP, HID, ES,
            (long)SLOT * FFNP, (long)FFN * HID, (long)SLOT);

    // G4: y[8192][1024] = CB @ eout   (BT, 128x128, nt=64)
    mfma_gemm<128, 128, 0, false, false, true, false, short, float>
        <<<dim3(64, 8, 1), 256, 0, stream>>>(
            CB, eoutT, y, HID, ES, ES, ES, HID, 0, 0, 0);
}

// Round 8
// 338.295 us; speedup vs baseline: 7.1013x; 1.1753x over previous
//
#include <hip/hip_runtime.h>
#include <hip/hip_bf16.h>
#include <math.h>

#define BS   8192   // batch*seq tokens
#define SEQQ 2048
#define HID  1024
#define ES   2048   // n_exp * slots
#define FFN  2730
#define FFNP 2752   // FFN padded to multiple of 32
#define NEXP 16
#define SLOT 128

typedef __attribute__((ext_vector_type(4))) float  f32x4;
typedef __attribute__((ext_vector_type(8))) short  short8;
typedef __attribute__((ext_vector_type(4))) short  short4v;

__device__ __forceinline__ short f2bf(float f) {
    union { float f; unsigned u; } v; v.f = f;
    unsigned r = v.u + 0x7fffu + ((v.u >> 16) & 1u);   // RNE
    return (short)(r >> 16);
}

// GEMM LDS swizzle (shorts). Row = 32 shorts, slot' = slot ^ ((row>>1)&3).
// Verified conflict-free rounds 4-7 (SQ_LDS_BANK_CONFLICT == 0).
__device__ __forceinline__ int swz(int row, int kk) {
    return (row << 5) + ((((kk >> 3) ^ (row >> 1)) & 3) << 3) + (kk & 7);
}

#define GLD16(gp, lp)                                                   \
    __builtin_amdgcn_global_load_lds(                                   \
        (__attribute__((address_space(1))) void*)(gp),                  \
        (__attribute__((address_space(3))) void*)(lp), 16, 0, 0)

// Transpose-tile swizzle for 64es x 256tok LDS tiles: tok' = tok ^ (sw(e)<<3),
// sw(e) = (e>>3) ^ (e&7). Bank-uniform for both scalar es-major writes and
// 16B tok-major reads (derivation: banks = full 32 coverage, 2 lanes/bank).
__device__ __forceinline__ int tsw(int e) { return ((e >> 3) ^ e) & 7; }

// ---------- fused prep: exp(logits) -> DT bf16 [ES][BS] + row/col sum partials ----------
__global__ __launch_bounds__(256) void exp_stats_kernel(const float* __restrict__ L,
                                                        short* __restrict__ DT,
                                                        float* __restrict__ rowpart,
                                                        float* __restrict__ colpart)
{
    const int t0 = (blockIdx.x & 31) << 8;       // 256-token tile
    const int et = blockIdx.x >> 5;              // es tile 0..31
    const int e0 = et << 6;                      // 64-es tile
    const int tid = threadIdx.x;
    const int lane = tid & 63;
    const int row = tid >> 3;                    // 0..31
    const int seg = tid & 7;                     // 0..7

    __shared__ short T[64 * 256];
    __shared__ float CP[4][64];

    float colacc[8];
    #pragma unroll
    for (int j = 0; j < 8; ++j) colacc[j] = 0.f;

    #pragma unroll
    for (int p = 0; p < 8; ++p) {
        const int tok = p * 32 + row;
        const float* src = L + (size_t)(t0 + tok) * ES + e0 + seg * 8;
        f32x4 a = *reinterpret_cast<const f32x4*>(src);
        f32x4 b = *reinterpret_cast<const f32x4*>(src + 4);
        float ex[8];
        #pragma unroll
        for (int j = 0; j < 4; ++j) ex[j]     = __expf(a[j]);
        #pragma unroll
        for (int j = 0; j < 4; ++j) ex[4 + j] = __expf(b[j]);
        float rs = 0.f;
        #pragma unroll
        for (int j = 0; j < 8; ++j) {
            const int e = seg * 8 + j;
            T[e * 256 + (tok ^ (((seg ^ j) & 7) << 3))] = f2bf(ex[j]);
            colacc[j] += ex[j];
            rs += ex[j];
        }
        rs += __shfl_xor(rs, 1, 64);
        rs += __shfl_xor(rs, 2, 64);
        rs += __shfl_xor(rs, 4, 64);
        if (seg == 0) rowpart[(size_t)(t0 + tok) * 32 + et] = rs;
    }
    #pragma unroll
    for (int j = 0; j < 8; ++j) {
        colacc[j] += __shfl_xor(colacc[j], 8, 64);
        colacc[j] += __shfl_xor(colacc[j], 16, 64);
        colacc[j] += __shfl_xor(colacc[j], 32, 64);
    }
    if ((lane >> 3) == 0) {
        #pragma unroll
        for (int j = 0; j < 8; ++j) CP[tid >> 6][(lane & 7) * 8 + j] = colacc[j];
    }
    __syncthreads();
    if (tid < 64)
        colpart[(size_t)(t0 >> 8) * ES + e0 + tid] =
            CP[0][tid] + CP[1][tid] + CP[2][tid] + CP[3][tid];
    // DT write-out (16B chunks, coalesced per es row)
    {
        const int e = tid >> 2, ts = tid & 3;
        const int sw = tsw(e) << 3;
        const size_t o = (size_t)(e0 + e) * BS + t0 + ts * 64;
        #pragma unroll
        for (int q = 0; q < 8; ++q) {
            short8 w = *reinterpret_cast<const short8*>(&T[e * 256 + ((ts * 64 + q * 8) ^ sw)]);
            *reinterpret_cast<short8*>(&DT[o + q * 8]) = w;
        }
    }
}

__global__ __launch_bounds__(256) void rrow_kernel(const float* __restrict__ rowpart,
                                                   float* __restrict__ crcp)
{
    const int t = blockIdx.x * 256 + threadIdx.x;
    const float* p = rowpart + (size_t)t * 32;
    float s = 0.f;
    #pragma unroll
    for (int j = 0; j < 8; ++j) {
        f32x4 v = *reinterpret_cast<const f32x4*>(p + 4 * j);
        s += (v[0] + v[1]) + (v[2] + v[3]);
    }
    crcp[t] = 1.f / s;
}

__global__ __launch_bounds__(256) void rcol_kernel(const float* __restrict__ colpart,
                                                   float* __restrict__ drcp)
{
    const int g = blockIdx.x * 256 + threadIdx.x;   // b*2048 + c
    const int b = g >> 11, c = g & 2047;
    float s = 0.f;
    #pragma unroll
    for (int ch = 0; ch < 8; ++ch)
        s += colpart[(size_t)(b * 8 + ch) * ES + c];
    drcp[g] = 1.f / s;
}

// ---------- CB bf16 [BS][ES] = DT^T (runs after reduce_xt frees the region) ----------
__global__ __launch_bounds__(256) void trans_cb_kernel(const short* __restrict__ DT,
                                                       short* __restrict__ CB)
{
    const int t0 = (blockIdx.x & 31) << 8;
    const int e0 = (blockIdx.x >> 5) << 6;
    const int tid = threadIdx.x;
    __shared__ short T[64 * 256];
    {
        const int e = tid >> 2, ts = tid & 3;
        const int sw = tsw(e) << 3;
        const size_t o = (size_t)(e0 + e) * BS + t0 + ts * 64;
        #pragma unroll
        for (int q = 0; q < 8; ++q) {
            short8 w = *reinterpret_cast<const short8*>(&DT[o + q * 8]);
            *reinterpret_cast<short8*>(&T[e * 256 + ((ts * 64 + q * 8) ^ sw)]) = w;
        }
    }
    __syncthreads();
    {
        const int row = tid >> 3, seg = tid & 7;
        #pragma unroll
        for (int p = 0; p < 8; ++p) {
            const int tok = p * 32 + row;
            short8 w;
            #pragma unroll
            for (int j = 0; j < 8; ++j) {
                const int e = seg * 8 + j;
                w[j] = T[e * 256 + (tok ^ (((seg ^ j) & 7) << 3))];
            }
            *reinterpret_cast<short8*>(&CB[(size_t)(t0 + tok) * ES + e0 + seg * 8]) = w;
        }
    }
}

// ---------- x fp32 [8192][1024] -> xT bf16 [1024][8192] ----------
__global__ __launch_bounds__(256) void transpose_x(const float* __restrict__ X,
                                                   short* __restrict__ XT)
{
    __shared__ short T[64][72];
    const int tid = threadIdx.x;
    const int k0 = blockIdx.x * 64;
    const int n0 = blockIdx.y * 64;
    {
        const int kk = tid >> 2;
        const int nn = (tid & 3) * 16;
        const float* src = X + (size_t)(k0 + kk) * HID + n0 + nn;
        #pragma unroll
        for (int j = 0; j < 4; ++j) {
            f32x4 v = *reinterpret_cast<const f32x4*>(src + 4 * j);
            short4v s;
            #pragma unroll
            for (int i = 0; i < 4; ++i) s[i] = f2bf(v[i]);
            *reinterpret_cast<short4v*>(&T[kk][nn + 4 * j]) = s;
        }
    }
    __syncthreads();
    {
        const int nn  = tid >> 2;
        const int kk4 = (tid & 3) * 16;
        short8 w0, w1;
        #pragma unroll
        for (int i = 0; i < 8; ++i) w0[i] = T[kk4 + i][nn];
        #pragma unroll
        for (int i = 0; i < 8; ++i) w1[i] = T[kk4 + 8 + i][nn];
        size_t o = (size_t)(n0 + nn) * BS + k0 + kk4;
        *reinterpret_cast<short8*>(&XT[o])     = w0;
        *reinterpret_cast<short8*>(&XT[o + 8]) = w1;
    }
}

// ---------- xt = bf16(sum_z drcp[z][c] * part[z][c][h]) (z = batch) ----------
__global__ __launch_bounds__(256) void reduce_xt(const float* __restrict__ P,
                                                 const float* __restrict__ drcp,
                                                 short* __restrict__ xt)
{
    const size_t i = ((size_t)blockIdx.x * 256 + threadIdx.x) * 4;
    const int c = (int)(i >> 10);
    const size_t CH = (size_t)ES * HID;
    f32x4 s0 = *reinterpret_cast<const f32x4*>(&P[i]);
    f32x4 s1 = *reinterpret_cast<const f32x4*>(&P[i + CH]);
    f32x4 s2 = *reinterpret_cast<const f32x4*>(&P[i + 2 * CH]);
    f32x4 s3 = *reinterpret_cast<const f32x4*>(&P[i + 3 * CH]);
    const float r0 = drcp[c], r1 = drcp[ES + c], r2 = drcp[2 * ES + c], r3 = drcp[3 * ES + c];
    short4v o;
    #pragma unroll
    for (int j = 0; j < 4; ++j)
        o[j] = f2bf((s0[j] * r0 + s1[j] * r1) + (s2[j] * r2 + s3[j] * r3));
    *reinterpret_cast<short4v*>(&xt[i]) = o;
}

// ---------------- bf16 MFMA GEMM body (gload_lds + dbuf, 1 barrier/step) ----------
// EPI: 0 none, 1 silu, 2 row-scale by aux[m]. See round-7 notes.
template<int BM, int BN, int EPI, bool NBND, bool KBND, bool BT, bool CT,
         typename TB, typename TC>
__device__ __forceinline__
void gemm_body(const short* __restrict__ A, const TB* __restrict__ B,
               TC* __restrict__ C, int Ndim, int Kdim,
               int lda, int ldb, int ldc,
               long sA, long sB, long sC, const float* __restrict__ aux)
{
    constexpr int BK = 32;
    A += (size_t)blockIdx.z * sA;
    B += (size_t)blockIdx.z * sB;
    C += (size_t)blockIdx.z * sC;
    const int m0 = blockIdx.x * BM;
    const int n0 = blockIdx.y * BN;
    const int tid  = threadIdx.x;
    const int lane = tid & 63;
    const int wid  = tid >> 6;
    const int wm = wid >> 1, wn = wid & 1;
    constexpr int WMT = BM / 2, WNT = BN / 2, MI = WMT / 16, NI = WNT / 16;
    constexpr int PA = BM / 64;
    constexpr int PB = BN / 64;

    __shared__ __align__(16) short As0[BM * 32], As1[BM * 32];
    __shared__ __align__(16) short Bs0[BN * 32], Bs1[BN * 32];

    f32x4 acc[MI][NI];
    #pragma unroll
    for (int mi = 0; mi < MI; ++mi)
        #pragma unroll
        for (int ni = 0; ni < NI; ++ni)
            acc[mi][ni] = (f32x4){0.f, 0.f, 0.f, 0.f};

    const int bnn = tid & 63;
    const int bks = (tid >> 6) * 8;

    auto ISSUE = [&](short* ASP, short* BSP, int kk, f32x4* bF) {
        #pragma unroll
        for (int p = 0; p < PA; ++p) {
            const int slot = p * 256 + tid;
            const int row  = slot >> 2;
            const int seg  = (slot & 3) ^ ((row >> 1) & 3);
            GLD16(&A[(size_t)(m0 + row) * lda + kk + seg * 8],
                  &ASP[(p * 256 + wid * 64) * 8]);
        }
        if constexpr (BT) {
            #pragma unroll
            for (int p = 0; p < PB; ++p) {
                const int slot = p * 256 + tid;
                const int row  = slot >> 2;
                const int seg  = (slot & 3) ^ ((row >> 1) & 3);
                GLD16(&B[(size_t)(n0 + row) * ldb + kk + seg * 8],
                      &BSP[(p * 256 + wid * 64) * 8]);
            }
        } else {
            const int n_ = n0 + bnn;
            const bool nok_ = (!NBND) || (n_ < Ndim);
            #pragma unroll
            for (int j = 0; j < 8; ++j) {
                int k_ = kk + bks + j;
                bool ok_ = nok_ && ((!KBND) || (k_ < Kdim));
                bF[j >> 2][j & 3] = ok_ ? (float)B[(size_t)k_ * ldb + n_] : 0.f;
            }
        }
    };

    auto PACKB = [&](short* BSP, const f32x4* bF) {
        short8 w;
        #pragma unroll
        for (int j = 0; j < 8; ++j) w[j] = f2bf(bF[j >> 2][j & 3]);
        *reinterpret_cast<short8*>(&BSP[swz(bnn, bks)]) = w;
    };

    auto COMPUTE = [&](const short* ASP, const short* BSP) {
        const int ar = lane & 15;
        const int ac = (lane >> 4) * 8;
        short8 af[MI], bf[NI];
        #pragma unroll
        for (int mi = 0; mi < MI; ++mi)
            af[mi] = *reinterpret_cast<const short8*>(&ASP[swz(wm * WMT + mi * 16 + ar, ac)]);
        #pragma unroll
        for (int ni = 0; ni < NI; ++ni)
            bf[ni] = *reinterpret_cast<const short8*>(&BSP[swz(wn * WNT + ni * 16 + ar, ac)]);
        #pragma unroll
        for (int mi = 0; mi < MI; ++mi)
            #pragma unroll
            for (int ni = 0; ni < NI; ++ni)
                acc[mi][ni] = __builtin_amdgcn_mfma_f32_16x16x32_bf16(
                    af[mi], bf[ni], acc[mi][ni], 0, 0, 0);
    };

    const int Kloop = KBND ? ((Kdim + 31) & ~31) : Kdim;
    const int nt = Kloop / BK;   // even, >= 2

    f32x4 bF0[2], bF1[2];
    ISSUE(As0, Bs0, 0, bF0);
    if constexpr (!BT) PACKB(Bs0, bF0);
    __syncthreads();

    for (int t = 0; t < nt; t += 2) {
        ISSUE(As1, Bs1, (t + 1) * BK, bF1);
        COMPUTE(As0, Bs0);
        if constexpr (!BT) PACKB(Bs1, bF1);
        __syncthreads();

        const bool p2 = (t + 2 < nt);
        if (p2) ISSUE(As0, Bs0, (t + 2) * BK, bF0);
        COMPUTE(As1, Bs1);
        if (p2) { if constexpr (!BT) PACKB(Bs0, bF0); }
        __syncthreads();
    }

    #pragma unroll
    for (int mi = 0; mi < MI; ++mi) {
        #pragma unroll
        for (int ni = 0; ni < NI; ++ni) {
            const int n = n0 + wn * WNT + ni * 16 + (lane & 15);
            if (NBND && n >= Ndim) continue;
            const int mbase = m0 + wm * WMT + mi * 16 + (lane >> 4) * 4;
            if constexpr (CT) {
                short4v sv;
                #pragma unroll
                for (int r = 0; r < 4; ++r) sv[r] = f2bf(acc[mi][ni][r]);
                *reinterpret_cast<short4v*>(&C[(size_t)n * ldc + mbase]) = sv;
            } else {
                #pragma unroll
                for (int r = 0; r < 4; ++r) {
                    float v = acc[mi][ni][r];
                    if (EPI == 1)      v = v / (1.f + __expf(-v));   // silu
                    else if (EPI == 2) v = v * aux[mbase + r];       // crcp
                    if constexpr (sizeof(TC) == 2) C[(size_t)(mbase + r) * ldc + n] = f2bf(v);
                    else                           C[(size_t)(mbase + r) * ldc + n] = v;
                }
            }
        }
    }
}

// ---------------- named GEMM wrappers (profiling disambiguation) ----------------
__global__ __launch_bounds__(256) void g1_gemm(const short* A, const short* B, float* C) {
    gemm_body<128, 128, 0, false, false, true, false, short, float>(
        A, B, C, HID, 2048, BS, BS, HID, 2048L, 2048L, (long)ES * HID, nullptr);
}
__global__ __launch_bounds__(256) void g1f_gemm(const short* A, const float* B, float* C) {
    gemm_body<128, 64, 0, false, false, false, false, float, float>(
        A, B, C, HID, 2048, BS, HID, HID, 2048L, 2048L * HID, (long)ES * HID, nullptr);
}
__global__ __launch_bounds__(256) void g2_gemm(const short* A, const float* B, short* C) {
    gemm_body<128, 64, 1, true, false, false, false, float, short>(
        A, B, C, FFN, HID, HID, FFN, FFNP,
        (long)SLOT * HID, (long)HID * FFN, (long)SLOT * FFNP, nullptr);
}
__global__ __launch_bounds__(256) void g3_gemm(const short* A, const float* B, short* C) {
    gemm_body<64, 64, 0, false, true, false, true, float, short>(
        A, B, C, HID, FFN, FFNP, HID, ES,
        (long)SLOT * FFNP, (long)FFN * HID, (long)SLOT, nullptr);
}
__global__ __launch_bounds__(256) void g4_gemm(const short* A, const short* B, float* C,
                                               const float* crcp) {
    gemm_body<128, 128, 2, false, false, true, false, short, float>(
        A, B, C, HID, ES, ES, ES, HID, 0, 0, 0, crcp);
}

// ---------------- launch ----------------

extern "C" void kernel_launch(void* const* d_in, const int* in_sizes, int n_in,
                              void* d_out, int out_size, void* d_ws, size_t ws_size,
                              hipStream_t stream)
{
    const float* x      = (const float*)d_in[0];
    const float* logits = (const float*)d_in[1];   // [BS][ES]
    const float* w_up   = (const float*)d_in[2];   // [16][1024][2730]
    const float* w_down = (const float*)d_in[3];   // [16][2730][1024]
    float* y = (float*)d_out;

    float* wsf     = (float*)d_ws;
    float* drcp    = wsf;                               // 4*2048
    float* crcp    = wsf + 8192;                        // 8192
    float* rowpart = wsf + 16384;                       // 8192*32
    float* colpart = rowpart + (size_t)8192 * 32;       // 32*2048
    short* DT      = (short*)(colpart + (size_t)32 * 2048);  // [2048][8192] bf16
    short* CB      = DT + (size_t)ES * BS;              // [8192][2048] bf16
    float* part    = (float*)CB;                        // [4][2048][1024] fp32 (alias)
    short* xt      = CB + (size_t)BS * ES;              // [2048][1024] bf16
    short* h       = xt + (size_t)ES * HID;             // [16][128][2752] bf16
    short* eoutT   = h + (size_t)NEXP * SLOT * FFNP;    // [1024][2048] bf16
    short* xT      = eoutT + (size_t)HID * ES;          // [1024][8192] bf16
    const size_t need_full = (size_t)((char*)(xT + (size_t)HID * BS) - (char*)d_ws);
    const bool use_bt = ws_size >= need_full;

    hipMemsetAsync(h, 0, (size_t)NEXP * SLOT * FFNP * sizeof(short), stream);

    exp_stats_kernel<<<1024, 256, 0, stream>>>(logits, DT, rowpart, colpart);
    rrow_kernel<<<32, 256, 0, stream>>>(rowpart, crcp);
    rcol_kernel<<<32, 256, 0, stream>>>(colpart, drcp);

    // G1: part[z] = expDT[:, batch z] @ x[batch z]   (K-split = batch, nt=64)
    if (use_bt) {
        transpose_x<<<dim3(128, 16, 1), 256, 0, stream>>>(x, xT);
        g1_gemm<<<dim3(16, 8, 4), 256, 0, stream>>>(DT, xT, part);
    } else {
        g1f_gemm<<<dim3(16, 16, 4), 256, 0, stream>>>(DT, x, part);
    }

    // xt = bf16(sum_z drcp[z] * part[z])
    reduce_xt<<<2048, 256, 0, stream>>>(part, drcp, xt);

    // CB = DT^T (overwrites part region; part fully consumed)
    trans_cb_kernel<<<1024, 256, 0, stream>>>(DT, CB);

    // G2: h[e] = silu(xt_e @ w_up_e)   (nt=32)
    g2_gemm<<<dim3(1, 43, NEXP), 256, 0, stream>>>(xt, w_up, h);

    // G3: eoutT = (h_e @ w_down_e)^T   (nt=86)
    g3_gemm<<<dim3(2, 16, NEXP), 256, 0, stream>>>(h, w_down, eoutT);

    // G4: y = expCB @ eout, row-scaled by crcp   (nt=64)
    g4_gemm<<<dim3(64, 8, 1), 256, 0, stream>>>(CB, eoutT, y, crcp);
}

// Round 9
// 331.833 us; speedup vs baseline: 7.2396x; 1.0195x over previous
//
#include <hip/hip_runtime.h>
#include <hip/hip_bf16.h>
#include <math.h>

#define BS   8192   // batch*seq tokens
#define SEQQ 2048
#define HID  1024
#define ES   2048   // n_exp * slots
#define FFN  2730
#define FFNP 2752   // FFN padded to multiple of 32
#define NEXP 16
#define SLOT 128

typedef __attribute__((ext_vector_type(4))) float  f32x4;
typedef __attribute__((ext_vector_type(8))) short  short8;
typedef __attribute__((ext_vector_type(4))) short  short4v;

__device__ __forceinline__ short f2bf(float f) {
    union { float f; unsigned u; } v; v.f = f;
    unsigned r = v.u + 0x7fffu + ((v.u >> 16) & 1u);   // RNE
    return (short)(r >> 16);
}

// GEMM LDS swizzle (shorts). Row = 32 shorts, slot' = slot ^ ((row>>1)&3).
// Verified conflict-free rounds 4-8 (SQ_LDS_BANK_CONFLICT == 0).
__device__ __forceinline__ int swz(int row, int kk) {
    return (row << 5) + ((((kk >> 3) ^ (row >> 1)) & 3) << 3) + (kk & 7);
}

#define GLD16(gp, lp)                                                   \
    __builtin_amdgcn_global_load_lds(                                   \
        (__attribute__((address_space(1))) void*)(gp),                  \
        (__attribute__((address_space(3))) void*)(lp), 16, 0, 0)

// Transpose-tile swizzle for 64es x 256tok LDS tiles (see round 7).
__device__ __forceinline__ int tsw(int e) { return ((e >> 3) ^ e) & 7; }

// ---------- fused prep: exp(logits) -> DT [ES][BS] + CB [BS][ES] + sum partials ----------
__global__ __launch_bounds__(256) void exp_stats_kernel(const float* __restrict__ L,
                                                        short* __restrict__ DT,
                                                        short* __restrict__ CB,
                                                        float* __restrict__ rowpart,
                                                        float* __restrict__ colpart)
{
    const int t0 = (blockIdx.x & 31) << 8;       // 256-token tile
    const int et = blockIdx.x >> 5;              // es tile 0..31
    const int e0 = et << 6;                      // 64-es tile
    const int tid = threadIdx.x;
    const int lane = tid & 63;
    const int row = tid >> 3;                    // 0..31
    const int seg = tid & 7;                     // 0..7

    __shared__ short T[64 * 256];
    __shared__ float CP[4][64];

    float colacc[8];
    #pragma unroll
    for (int j = 0; j < 8; ++j) colacc[j] = 0.f;

    #pragma unroll
    for (int p = 0; p < 8; ++p) {
        const int tok = p * 32 + row;
        const float* src = L + (size_t)(t0 + tok) * ES + e0 + seg * 8;
        f32x4 a = *reinterpret_cast<const f32x4*>(src);
        f32x4 b = *reinterpret_cast<const f32x4*>(src + 4);
        float ex[8];
        #pragma unroll
        for (int j = 0; j < 4; ++j) ex[j]     = __expf(a[j]);
        #pragma unroll
        for (int j = 0; j < 4; ++j) ex[4 + j] = __expf(b[j]);
        float rs = 0.f;
        #pragma unroll
        for (int j = 0; j < 8; ++j) {
            const int e = seg * 8 + j;
            T[e * 256 + (tok ^ (((seg ^ j) & 7) << 3))] = f2bf(ex[j]);
            colacc[j] += ex[j];
            rs += ex[j];
        }
        rs += __shfl_xor(rs, 1, 64);
        rs += __shfl_xor(rs, 2, 64);
        rs += __shfl_xor(rs, 4, 64);
        if (seg == 0) rowpart[(size_t)(t0 + tok) * 32 + et] = rs;
    }
    #pragma unroll
    for (int j = 0; j < 8; ++j) {
        colacc[j] += __shfl_xor(colacc[j], 8, 64);
        colacc[j] += __shfl_xor(colacc[j], 16, 64);
        colacc[j] += __shfl_xor(colacc[j], 32, 64);
    }
    if ((lane >> 3) == 0) {
        #pragma unroll
        for (int j = 0; j < 8; ++j) CP[tid >> 6][(lane & 7) * 8 + j] = colacc[j];
    }
    __syncthreads();
    if (tid < 64)
        colpart[(size_t)(t0 >> 8) * ES + e0 + tid] =
            CP[0][tid] + CP[1][tid] + CP[2][tid] + CP[3][tid];
    // DT write-out (tok-contiguous 16B chunks per es row)
    {
        const int e = tid >> 2, ts = tid & 3;
        const int sw = tsw(e) << 3;
        const size_t o = (size_t)(e0 + e) * BS + t0 + ts * 64;
        #pragma unroll
        for (int q = 0; q < 8; ++q) {
            short8 w = *reinterpret_cast<const short8*>(&T[e * 256 + ((ts * 64 + q * 8) ^ sw)]);
            *reinterpret_cast<short8*>(&DT[o + q * 8]) = w;
        }
    }
    // CB write-out (es-contiguous 16B chunks per token; fused former trans_cb)
    {
        #pragma unroll
        for (int p = 0; p < 8; ++p) {
            const int tok = p * 32 + row;
            short8 w;
            #pragma unroll
            for (int j = 0; j < 8; ++j) {
                const int e = seg * 8 + j;
                w[j] = T[e * 256 + (tok ^ (((seg ^ j) & 7) << 3))];
            }
            *reinterpret_cast<short8*>(&CB[(size_t)(t0 + tok) * ES + e0 + seg * 8]) = w;
        }
    }
}

__global__ __launch_bounds__(256) void rrow_kernel(const float* __restrict__ rowpart,
                                                   float* __restrict__ crcp)
{
    const int t = blockIdx.x * 256 + threadIdx.x;
    const float* p = rowpart + (size_t)t * 32;
    float s = 0.f;
    #pragma unroll
    for (int j = 0; j < 8; ++j) {
        f32x4 v = *reinterpret_cast<const f32x4*>(p + 4 * j);
        s += (v[0] + v[1]) + (v[2] + v[3]);
    }
    crcp[t] = 1.f / s;
}

__global__ __launch_bounds__(256) void rcol_kernel(const float* __restrict__ colpart,
                                                   float* __restrict__ drcp)
{
    const int g = blockIdx.x * 256 + threadIdx.x;   // b*2048 + c
    const int b = g >> 11, c = g & 2047;
    float s = 0.f;
    #pragma unroll
    for (int ch = 0; ch < 8; ++ch)
        s += colpart[(size_t)(b * 8 + ch) * ES + c];
    drcp[g] = 1.f / s;
}

// ---------- x fp32 [8192][1024] -> xT bf16 [1024][8192] ----------
__global__ __launch_bounds__(256) void transpose_x(const float* __restrict__ X,
                                                   short* __restrict__ XT)
{
    __shared__ short T[64][72];
    const int tid = threadIdx.x;
    const int k0 = blockIdx.x * 64;
    const int n0 = blockIdx.y * 64;
    {
        const int kk = tid >> 2;
        const int nn = (tid & 3) * 16;
        const float* src = X + (size_t)(k0 + kk) * HID + n0 + nn;
        #pragma unroll
        for (int j = 0; j < 4; ++j) {
            f32x4 v = *reinterpret_cast<const f32x4*>(src + 4 * j);
            short4v s;
            #pragma unroll
            for (int i = 0; i < 4; ++i) s[i] = f2bf(v[i]);
            *reinterpret_cast<short4v*>(&T[kk][nn + 4 * j]) = s;
        }
    }
    __syncthreads();
    {
        const int nn  = tid >> 2;
        const int kk4 = (tid & 3) * 16;
        short8 w0, w1;
        #pragma unroll
        for (int i = 0; i < 8; ++i) w0[i] = T[kk4 + i][nn];
        #pragma unroll
        for (int i = 0; i < 8; ++i) w1[i] = T[kk4 + 8 + i][nn];
        size_t o = (size_t)(n0 + nn) * BS + k0 + kk4;
        *reinterpret_cast<short8*>(&XT[o])     = w0;
        *reinterpret_cast<short8*>(&XT[o + 8]) = w1;
    }
}

// ---------- xt = bf16(sum_z drcp[z][c] * part[z][c][h]) (z = batch) ----------
__global__ __launch_bounds__(256) void reduce_xt(const float* __restrict__ P,
                                                 const float* __restrict__ drcp,
                                                 short* __restrict__ xt)
{
    const size_t i = ((size_t)blockIdx.x * 256 + threadIdx.x) * 4;
    const int c = (int)(i >> 10);
    const size_t CH = (size_t)ES * HID;
    f32x4 s0 = *reinterpret_cast<const f32x4*>(&P[i]);
    f32x4 s1 = *reinterpret_cast<const f32x4*>(&P[i + CH]);
    f32x4 s2 = *reinterpret_cast<const f32x4*>(&P[i + 2 * CH]);
    f32x4 s3 = *reinterpret_cast<const f32x4*>(&P[i + 3 * CH]);
    const float r0 = drcp[c], r1 = drcp[ES + c], r2 = drcp[2 * ES + c], r3 = drcp[3 * ES + c];
    short4v o;
    #pragma unroll
    for (int j = 0; j < 4; ++j)
        o[j] = f2bf((s0[j] * r0 + s1[j] * r1) + (s2[j] * r2 + s3[j] * r3));
    *reinterpret_cast<short4v*>(&xt[i]) = o;
}

// ---------------- bf16 MFMA GEMM body (gload_lds + dbuf, 1 barrier/step) ----------
// EPI: 0 none, 1 silu, 2 row-scale by aux[m].
// PADW: store n >= Ndim too (acc==0 there since B staged 0) — writes exact-zero pad.
template<int BM, int BN, int EPI, bool NBND, bool KBND, bool BT, bool CT, bool PADW,
         typename TB, typename TC>
__device__ __forceinline__
void gemm_body(const short* __restrict__ A, const TB* __restrict__ B,
               TC* __restrict__ C, int Ndim, int Kdim,
               int lda, int ldb, int ldc,
               long sA, long sB, long sC, const float* __restrict__ aux)
{
    constexpr int BK = 32;
    A += (size_t)blockIdx.z * sA;
    B += (size_t)blockIdx.z * sB;
    C += (size_t)blockIdx.z * sC;
    const int m0 = blockIdx.x * BM;
    const int n0 = blockIdx.y * BN;
    const int tid  = threadIdx.x;
    const int lane = tid & 63;
    const int wid  = tid >> 6;
    const int wm = wid >> 1, wn = wid & 1;
    constexpr int WMT = BM / 2, WNT = BN / 2, MI = WMT / 16, NI = WNT / 16;
    constexpr int PA = BM / 64;
    constexpr int PB = BN / 64;

    __shared__ __align__(16) short As0[BM * 32], As1[BM * 32];
    __shared__ __align__(16) short Bs0[BN * 32], Bs1[BN * 32];

    f32x4 acc[MI][NI];
    #pragma unroll
    for (int mi = 0; mi < MI; ++mi)
        #pragma unroll
        for (int ni = 0; ni < NI; ++ni)
            acc[mi][ni] = (f32x4){0.f, 0.f, 0.f, 0.f};

    const int bnn = tid & 63;
    const int bks = (tid >> 6) * 8;

    auto ISSUE = [&](short* ASP, short* BSP, int kk, f32x4* bF) {
        #pragma unroll
        for (int p = 0; p < PA; ++p) {
            const int slot = p * 256 + tid;
            const int row  = slot >> 2;
            const int seg  = (slot & 3) ^ ((row >> 1) & 3);
            GLD16(&A[(size_t)(m0 + row) * lda + kk + seg * 8],
                  &ASP[(p * 256 + wid * 64) * 8]);
        }
        if constexpr (BT) {
            #pragma unroll
            for (int p = 0; p < PB; ++p) {
                const int slot = p * 256 + tid;
                const int row  = slot >> 2;
                const int seg  = (slot & 3) ^ ((row >> 1) & 3);
                GLD16(&B[(size_t)(n0 + row) * ldb + kk + seg * 8],
                      &BSP[(p * 256 + wid * 64) * 8]);
            }
        } else {
            const int n_ = n0 + bnn;
            const bool nok_ = (!NBND) || (n_ < Ndim);
            #pragma unroll
            for (int j = 0; j < 8; ++j) {
                int k_ = kk + bks + j;
                bool ok_ = nok_ && ((!KBND) || (k_ < Kdim));
                bF[j >> 2][j & 3] = ok_ ? (float)B[(size_t)k_ * ldb + n_] : 0.f;
            }
        }
    };

    auto PACKB = [&](short* BSP, const f32x4* bF) {
        short8 w;
        #pragma unroll
        for (int j = 0; j < 8; ++j) w[j] = f2bf(bF[j >> 2][j & 3]);
        *reinterpret_cast<short8*>(&BSP[swz(bnn, bks)]) = w;
    };

    auto COMPUTE = [&](const short* ASP, const short* BSP) {
        const int ar = lane & 15;
        const int ac = (lane >> 4) * 8;
        short8 af[MI], bf[NI];
        #pragma unroll
        for (int mi = 0; mi < MI; ++mi)
            af[mi] = *reinterpret_cast<const short8*>(&ASP[swz(wm * WMT + mi * 16 + ar, ac)]);
        #pragma unroll
        for (int ni = 0; ni < NI; ++ni)
            bf[ni] = *reinterpret_cast<const short8*>(&BSP[swz(wn * WNT + ni * 16 + ar, ac)]);
        #pragma unroll
        for (int mi = 0; mi < MI; ++mi)
            #pragma unroll
            for (int ni = 0; ni < NI; ++ni)
                acc[mi][ni] = __builtin_amdgcn_mfma_f32_16x16x32_bf16(
                    af[mi], bf[ni], acc[mi][ni], 0, 0, 0);
    };

    const int Kloop = KBND ? ((Kdim + 31) & ~31) : Kdim;
    const int nt = Kloop / BK;   // even, >= 2

    f32x4 bF0[2], bF1[2];
    ISSUE(As0, Bs0, 0, bF0);
    if constexpr (!BT) PACKB(Bs0, bF0);
    __syncthreads();

    for (int t = 0; t < nt; t += 2) {
        ISSUE(As1, Bs1, (t + 1) * BK, bF1);
        COMPUTE(As0, Bs0);
        if constexpr (!BT) PACKB(Bs1, bF1);
        __syncthreads();

        const bool p2 = (t + 2 < nt);
        if (p2) ISSUE(As0, Bs0, (t + 2) * BK, bF0);
        COMPUTE(As1, Bs1);
        if (p2) { if constexpr (!BT) PACKB(Bs0, bF0); }
        __syncthreads();
    }

    #pragma unroll
    for (int mi = 0; mi < MI; ++mi) {
        #pragma unroll
        for (int ni = 0; ni < NI; ++ni) {
            const int n = n0 + wn * WNT + ni * 16 + (lane & 15);
            if (NBND && !PADW && n >= Ndim) continue;
            const int mbase = m0 + wm * WMT + mi * 16 + (lane >> 4) * 4;
            if constexpr (CT) {
                short4v sv;
                #pragma unroll
                for (int r = 0; r < 4; ++r) sv[r] = f2bf(acc[mi][ni][r]);
                *reinterpret_cast<short4v*>(&C[(size_t)n * ldc + mbase]) = sv;
            } else {
                #pragma unroll
                for (int r = 0; r < 4; ++r) {
                    float v = acc[mi][ni][r];
                    if (EPI == 1)      v = v / (1.f + __expf(-v));   // silu
                    else if (EPI == 2) v = v * aux[mbase + r];       // crcp
                    if constexpr (sizeof(TC) == 2) C[(size_t)(mbase + r) * ldc + n] = f2bf(v);
                    else                           C[(size_t)(mbase + r) * ldc + n] = v;
                }
            }
        }
    }
}

// ---------------- named GEMM wrappers ----------------
__global__ __launch_bounds__(256) void g1_gemm(const short* A, const short* B, float* C) {
    gemm_body<128, 128, 0, false, false, true, false, false, short, float>(
        A, B, C, HID, 2048, BS, BS, HID, 2048L, 2048L, (long)ES * HID, nullptr);
}
__global__ __launch_bounds__(256) void g1f_gemm(const short* A, const float* B, float* C) {
    gemm_body<128, 64, 0, false, false, false, false, false, float, float>(
        A, B, C, HID, 2048, BS, HID, HID, 2048L, 2048L * HID, (long)ES * HID, nullptr);
}
__global__ __launch_bounds__(256) void g2_gemm(const short* A, const float* B, short* C) {
    gemm_body<128, 64, 1, true, false, false, false, true, float, short>(
        A, B, C, FFN, HID, HID, FFN, FFNP,
        (long)SLOT * HID, (long)HID * FFN, (long)SLOT * FFNP, nullptr);
}
__global__ __launch_bounds__(256) void g3_gemm(const short* A, const float* B, short* C) {
    gemm_body<64, 64, 0, false, true, false, true, false, float, short>(
        A, B, C, HID, FFN, FFNP, HID, ES,
        (long)SLOT * FFNP, (long)FFN * HID, (long)SLOT, nullptr);
}
__global__ __launch_bounds__(256) void g4_gemm(const short* A, const short* B, float* C,
                                               const float* crcp) {
    gemm_body<128, 128, 2, false, false, true, false, false, short, float>(
        A, B, C, HID, ES, ES, ES, HID, 0, 0, 0, crcp);
}

// ---------------- launch ----------------

extern "C" void kernel_launch(void* const* d_in, const int* in_sizes, int n_in,
                              void* d_out, int out_size, void* d_ws, size_t ws_size,
                              hipStream_t stream)
{
    const float* x      = (const float*)d_in[0];
    const float* logits = (const float*)d_in[1];   // [BS][ES]
    const float* w_up   = (const float*)d_in[2];   // [16][1024][2730]
    const float* w_down = (const float*)d_in[3];   // [16][2730][1024]
    float* y = (float*)d_out;

    float* wsf     = (float*)d_ws;
    float* drcp    = wsf;                               // 4*2048
    float* crcp    = wsf + 8192;                        // 8192
    float* rowpart = wsf + 16384;                       // 8192*32
    float* colpart = rowpart + (size_t)8192 * 32;       // 32*2048
    short* DT      = (short*)(colpart + (size_t)32 * 2048);  // [2048][8192] bf16
    short* CB      = DT + (size_t)ES * BS;              // [8192][2048] bf16
    float* part    = (float*)(CB + (size_t)BS * ES);    // [4][2048][1024] fp32 (no alias)
    short* xt      = (short*)(part + (size_t)4 * ES * HID); // [2048][1024] bf16
    short* h       = xt + (size_t)ES * HID;             // [16][128][2752] bf16
    short* eoutT   = h + (size_t)NEXP * SLOT * FFNP;    // [1024][2048] bf16
    short* xT      = eoutT + (size_t)HID * ES;          // [1024][8192] bf16
    const size_t need_full = (size_t)((char*)(xT + (size_t)HID * BS) - (char*)d_ws);
    const bool use_bt = ws_size >= need_full;

    // NOTE: no memset. h pad columns (2730..2751) are written as exact zeros by
    // g2 (PADW store of acc==0); g3 additionally zeroes B for k >= 2730, so pad
    // contributions vanish regardless.

    exp_stats_kernel<<<1024, 256, 0, stream>>>(logits, DT, CB, rowpart, colpart);
    rrow_kernel<<<32, 256, 0, stream>>>(rowpart, crcp);
    rcol_kernel<<<32, 256, 0, stream>>>(colpart, drcp);

    // G1: part[z] = expDT[:, batch z] @ x[batch z]   (K-split = batch, nt=64)
    if (use_bt) {
        transpose_x<<<dim3(128, 16, 1), 256, 0, stream>>>(x, xT);
        g1_gemm<<<dim3(16, 8, 4), 256, 0, stream>>>(DT, xT, part);
    } else {
        g1f_gemm<<<dim3(16, 16, 4), 256, 0, stream>>>(DT, x, part);
    }

    // xt = bf16(sum_z drcp[z] * part[z])
    reduce_xt<<<2048, 256, 0, stream>>>(part, drcp, xt);

    // G2: h[e] = silu(xt_e @ w_up_e), pad cols written as 0   (nt=32)
    g2_gemm<<<dim3(1, 43, NEXP), 256, 0, stream>>>(xt, w_up, h);

    // G3: eoutT = (h_e @ w_down_e)^T   (nt=86)
    g3_gemm<<<dim3(2, 16, NEXP), 256, 0, stream>>>(h, w_down, eoutT);

    // G4: y = expCB @ eout, row-scaled by crcp   (nt=64)
    g4_gemm<<<dim3(64, 8, 1), 256, 0, stream>>>(CB, eoutT, y, crcp);
}